// Round 2
// baseline (776.391 us; speedup 1.0000x reference)
//
#include <hip/hip_runtime.h>
#include <hip/hip_bf16.h>
#include <stdint.h>

// ============================================================================
// MoE Autoencoder (N=8192, D_IN=2048, H=1024, E=8).  f32 in / f32 out,
// bf16-tolerance (0.0625 floor) => bf16 MFMA compute allowed.
// Round 2:
//   - all inputs read as FLOAT32 (round-1 NaN = f32 misread as bf16)
//   - weights transpose+cast f32->bf16; x cast in-GEMM (reg-staged A)
//   - m97-structure 128x128 bf16 GEMMs
//   - gate from f32 h; rows with top2 logit gap < 0.02 recomputed in f64
//     (argmax flips vs f32 reference are fatal at 0.0625 threshold)
//   - expert counts taken AFTER fixup; counting-sort dispatch
// ============================================================================

using bf16 = __hip_bfloat16;
typedef __bf16 bf16x8 __attribute__((ext_vector_type(8)));
typedef float f32x4 __attribute__((ext_vector_type(4)));

static constexpr int NROWS = 8192;
static constexpr int DIN   = 2048;
static constexpr int HD    = 1024;
static constexpr int NEXP  = 8;
static constexpr int MAX_TILES = 72;     // sum_e ceil(cnt_e/128) <= 64+7
static constexpr int MAXFLAG = 512;      // expected ~100-250 flagged rows
#define GAPTHR 0.02f

__device__ __forceinline__ uint16_t f2u(float f) {
  bf16 h = __float2bfloat16(f);
  uint16_t u; __builtin_memcpy(&u, &h, 2); return u;
}

typedef const __attribute__((address_space(1))) void* gas_ptr;
typedef __attribute__((address_space(3))) void* las_ptr;
__device__ __forceinline__ void async16(void* lds, const void* g) {
  __builtin_amdgcn_global_load_lds((gas_ptr)g, (las_ptr)lds, 16, 0, 0);
}

// ----------------------------------------------------------------------------
// 64x64-tile transpose + cast f32 -> bf16: out[C][R] = bf16(in[R][C]).
// ----------------------------------------------------------------------------
__global__ __launch_bounds__(256)
void tcast_k(const float* __restrict__ in, uint16_t* __restrict__ out,
             int R, int C) {
  __shared__ float tile[64 * 65];
  const int t  = threadIdx.x;
  const int C0 = blockIdx.x * 64, R0 = blockIdx.y * 64;
  in  += (size_t)blockIdx.z * R * C;
  out += (size_t)blockIdx.z * R * C;
  const int cl = (t & 7) * 8;
#pragma unroll
  for (int p = 0; p < 2; ++p) {
    const int r = p * 32 + (t >> 3);
    const float* src = in + (size_t)(R0 + r) * C + C0 + cl;
    float4 v0 = *(const float4*)(src);
    float4 v1 = *(const float4*)(src + 4);
    float* dst = &tile[r * 65 + cl];
    dst[0] = v0.x; dst[1] = v0.y; dst[2] = v0.z; dst[3] = v0.w;
    dst[4] = v1.x; dst[5] = v1.y; dst[6] = v1.z; dst[7] = v1.w;
  }
  __syncthreads();
#pragma unroll
  for (int p = 0; p < 2; ++p) {
    const int oc = p * 32 + (t >> 3);
    uint16_t tmp[8];
#pragma unroll
    for (int j = 0; j < 8; ++j) tmp[j] = f2u(tile[(cl + j) * 65 + oc]);
    int4 v; __builtin_memcpy(&v, tmp, 16);
    *(int4*)(out + (size_t)(C0 + oc) * R + R0 + cl) = v;
  }
}

// ----------------------------------------------------------------------------
// 128x128-tile GEMM, BK=64, 4 waves:  C = epilogue(A[M,K] @ BT[N,K]^T)
// MODE 0: enc  — A is f32 (reg-stage cast); relu(acc+b) -> h_bf (bf16) + h32
// MODE 1: exp  — gathered rows; (acc + b_e) * scale[orig], scattered (bf16)
// MODE 2: mlp  — C16[r,c] += (acc + b) * scale[r]         (bf16 RMW)
// MODE 3: dec  — C32 = acc + b                            (f32 out)
// ----------------------------------------------------------------------------
template<int MODE>
__global__ __launch_bounds__(256)
void gemm_kernel(const void* __restrict__ Av, const uint16_t* __restrict__ BT,
                 uint16_t* __restrict__ C16, float* __restrict__ C32,
                 const float* __restrict__ biasf, float* __restrict__ h32,
                 const int* __restrict__ rowperm, const int* __restrict__ tinfo,
                 const float* __restrict__ scale, int M, int N, int K)
{
  const int t = threadIdx.x;
  const int mtile = blockIdx.x, ntile = blockIdx.y;

  int e = 0, row0 = 0, rowend = 0;
  if constexpr (MODE == 1) {
    const int nt = tinfo[0];
    if (mtile >= nt) return;
    e      = tinfo[1 + mtile * 3 + 0];
    row0   = tinfo[1 + mtile * 3 + 1];
    rowend = tinfo[1 + mtile * 3 + 2];
  }

  __shared__ uint16_t As[128 * 64];
  __shared__ uint16_t Bs[128 * 64];

  const int kcol = (t & 7) * 8;
  const char* asrc[4];
  const uint16_t* bsrc[4];
  const int aelt = (MODE == 0) ? 4 : 2;   // bytes per A element
#pragma unroll
  for (int c = 0; c < 4; ++c) {
    const int r = c * 32 + (t >> 3);
    int arow;
    if constexpr (MODE == 1) {
      int pr = row0 + r;
      if (pr > rowend - 1) pr = rowend - 1;     // pad rows clamped, masked later
      arow = rowperm[pr];
    } else {
      arow = mtile * 128 + r;
    }
    asrc[c] = (const char*)Av + ((size_t)arow * K + kcol) * aelt;
    size_t brow = (size_t)ntile * 128 + r;
    if constexpr (MODE == 1) brow += (size_t)e * N;   // expWT: [E][N][K]
    bsrc[c] = BT + brow * (size_t)K + kcol;
  }

  f32x4 acc[4][4];
  const f32x4 zero = {0.f, 0.f, 0.f, 0.f};
#pragma unroll
  for (int i = 0; i < 4; ++i)
#pragma unroll
    for (int j = 0; j < 4; ++j) acc[i][j] = zero;

  const int wid = t >> 6, lane = t & 63;
  const int wm = wid >> 1, wn = wid & 1;
  const int frow = lane & 15;
  const int fk = (lane >> 4) * 8;

  const int nk = K >> 6;
  for (int kt = 0; kt < nk; ++kt) {
    if constexpr (MODE == 0) {
#pragma unroll
      for (int c = 0; c < 4; ++c) {
        const float* s = (const float*)asrc[c] + kt * 64;
        float4 v0 = *(const float4*)(s);
        float4 v1 = *(const float4*)(s + 4);
        uint16_t tmp[8];
        tmp[0] = f2u(v0.x); tmp[1] = f2u(v0.y); tmp[2] = f2u(v0.z); tmp[3] = f2u(v0.w);
        tmp[4] = f2u(v1.x); tmp[5] = f2u(v1.y); tmp[6] = f2u(v1.z); tmp[7] = f2u(v1.w);
        int4 pv; __builtin_memcpy(&pv, tmp, 16);
        *(int4*)&As[c * 2048 + t * 8] = pv;       // r*64+kcol == t*8
      }
#pragma unroll
      for (int c = 0; c < 4; ++c)
        async16(&Bs[c * 2048 + t * 8], bsrc[c] + kt * 64);
    } else {
#pragma unroll
      for (int c = 0; c < 4; ++c) {
        async16(&As[c * 2048 + t * 8], (const uint16_t*)asrc[c] + kt * 64);
        async16(&Bs[c * 2048 + t * 8], bsrc[c] + kt * 64);
      }
    }
    __syncthreads();
#pragma unroll
    for (int kk = 0; kk < 2; ++kk) {
      bf16x8 af[4], bfr[4];
#pragma unroll
      for (int mi = 0; mi < 4; ++mi)
        af[mi] = *reinterpret_cast<const bf16x8*>(
            &As[(wm * 64 + mi * 16 + frow) * 64 + kk * 32 + fk]);
#pragma unroll
      for (int ni = 0; ni < 4; ++ni)
        bfr[ni] = *reinterpret_cast<const bf16x8*>(
            &Bs[(wn * 64 + ni * 16 + frow) * 64 + kk * 32 + fk]);
#pragma unroll
      for (int mi = 0; mi < 4; ++mi)
#pragma unroll
        for (int ni = 0; ni < 4; ++ni)
          acc[mi][ni] = __builtin_amdgcn_mfma_f32_16x16x32_bf16(
              af[mi], bfr[ni], acc[mi][ni], 0, 0, 0);
    }
    __syncthreads();
  }

  // epilogue — C/D layout: col = lane&15, row = (lane>>4)*4 + j   [m89]
  const int nbase = ntile * 128 + wn * 64;
  const int rbase = wm * 64 + (lane >> 4) * 4;
  const int cbase = lane & 15;
#pragma unroll
  for (int mi = 0; mi < 4; ++mi) {
#pragma unroll
    for (int j = 0; j < 4; ++j) {
      const int rr = rbase + mi * 16 + j;
      if constexpr (MODE == 1) {
        const int pr = row0 + rr;
        if (pr < rowend) {
          const int orig = rowperm[pr];
          const float sc = scale[orig];
          uint16_t* dst = C16 + (size_t)orig * N;
#pragma unroll
          for (int ni = 0; ni < 4; ++ni) {
            const int gc = nbase + ni * 16 + cbase;
            dst[gc] = f2u((acc[mi][ni][j] + biasf[e * N + gc]) * sc);
          }
        }
      } else {
        const int gr = mtile * 128 + rr;
#pragma unroll
        for (int ni = 0; ni < 4; ++ni) {
          const int gc = nbase + ni * 16 + cbase;
          float v = acc[mi][ni][j] + biasf[gc];
          if constexpr (MODE == 0) {
            v = fmaxf(v, 0.f);
            C16[(size_t)gr * N + gc] = f2u(v);
            h32[(size_t)gr * N + gc] = v;
          } else if constexpr (MODE == 2) {
            const uint16_t pu = C16[(size_t)gr * N + gc];
            uint32_t pb = ((uint32_t)pu) << 16;
            float prev; __builtin_memcpy(&prev, &pb, 4);
            C16[(size_t)gr * N + gc] = f2u(prev + v * scale[gr]);
          } else {
            C32[(size_t)gr * N + gc] = v;
          }
        }
      }
    }
  }
}

// ----------------------------------------------------------------------------
// Gate: logits = h32 @ gate_W (f32), coef = softmax(h32 @ coef_W + cb).
// One wave per row. Flags rows with top2 gap < GAPTHR for f64 fixup.
// ----------------------------------------------------------------------------
__global__ __launch_bounds__(256)
void gate_kernel(const float* __restrict__ h32, const float* __restrict__ gW,
                 const float* __restrict__ cW, const float* __restrict__ cb,
                 int* __restrict__ eidx, float* __restrict__ s0,
                 float* __restrict__ c1, int* __restrict__ nflag,
                 int* __restrict__ flaglist)
{
  const int lane = threadIdx.x & 63;
  const int row  = blockIdx.x * 4 + (threadIdx.x >> 6);
  const float* hrow = h32 + (size_t)row * HD;
  float a[10];
#pragma unroll
  for (int i = 0; i < 10; ++i) a[i] = 0.f;
  for (int kk = 0; kk < HD / 64; ++kk) {
    const int k = kk * 64 + lane;
    const float hv = hrow[k];
    float4 g0 = *(const float4*)(gW + (size_t)k * 8);
    float4 g1 = *(const float4*)(gW + (size_t)k * 8 + 4);
    a[0] += hv * g0.x; a[1] += hv * g0.y; a[2] += hv * g0.z; a[3] += hv * g0.w;
    a[4] += hv * g1.x; a[5] += hv * g1.y; a[6] += hv * g1.z; a[7] += hv * g1.w;
    float2 cv = *(const float2*)(cW + (size_t)k * 2);
    a[8] += hv * cv.x; a[9] += hv * cv.y;
  }
#pragma unroll
  for (int off = 32; off > 0; off >>= 1) {
#pragma unroll
    for (int i = 0; i < 10; ++i) a[i] += __shfl_xor(a[i], off);
  }
  if (lane == 0) {
    int best = 0; float bm = a[0];
#pragma unroll
    for (int e2 = 1; e2 < 8; ++e2) if (a[e2] > bm) { bm = a[e2]; best = e2; }
    float sec = -3.0e38f;
#pragma unroll
    for (int e2 = 0; e2 < 8; ++e2) if (e2 != best) sec = fmaxf(sec, a[e2]);
    float s = 0.f;
#pragma unroll
    for (int e2 = 0; e2 < 8; ++e2) s += expf(a[e2] - bm);
    const float p  = 1.f / s;
    const float l0 = a[8] + cb[0], l1 = a[9] + cb[1];
    const float mx = fmaxf(l0, l1);
    const float e0 = expf(l0 - mx), e1 = expf(l1 - mx);
    const float inv = 1.f / (e0 + e1);
    eidx[row] = best;
    s0[row]   = p * (e0 * inv);
    c1[row]   = e1 * inv;
    if (bm - sec < GAPTHR) {
      int fi = atomicAdd(nflag, 1);
      if (fi < MAXFLAG) flaglist[fi] = row;
    }
  }
}

// fixup1: z = x @ enc_W in f64 for flagged rows. block b owns cols 4b..4b+3.
__global__ __launch_bounds__(256)
void fixup1_kernel(const float* __restrict__ x, const float* __restrict__ encW,
                   const int* __restrict__ flaglist, const int* __restrict__ nflag,
                   float* __restrict__ z32)
{
  int nf = *nflag; if (nf > MAXFLAG) nf = MAXFLAG;
  const int t = threadIdx.x;
  const int j = blockIdx.x * 4 + (t & 3);
  for (int rp = (t >> 2); rp < nf; rp += 64) {
    const float* xr = x + (size_t)flaglist[rp] * DIN;
    double a0 = 0, a1 = 0, a2 = 0, a3 = 0;
    for (int k = 0; k < DIN; k += 4) {
      float4 xv = *(const float4*)(xr + k);
      const float* wc = encW + (size_t)k * HD + j;
      a0 += (double)xv.x * (double)wc[0];
      a1 += (double)xv.y * (double)wc[HD];
      a2 += (double)xv.z * (double)wc[2 * HD];
      a3 += (double)xv.w * (double)wc[3 * HD];
    }
    z32[(size_t)rp * HD + j] = (float)(a0 + a1 + a2 + a3);
  }
}

// fixup2: f64 gate logits + coef for flagged rows; overwrite eidx/s0/c1.
__global__ __launch_bounds__(256)
void fixup2_kernel(const float* __restrict__ z32, const float* __restrict__ encB,
                   const float* __restrict__ gW, const float* __restrict__ cW,
                   const float* __restrict__ cb, const int* __restrict__ flaglist,
                   const int* __restrict__ nflag, int* __restrict__ eidx,
                   float* __restrict__ s0, float* __restrict__ c1)
{
  __shared__ double red[4][10];
  int nf = *nflag; if (nf > MAXFLAG) nf = MAXFLAG;
  const int t = threadIdx.x, lane = t & 63, w = t >> 6;
  for (int f = blockIdx.x; f < nf; f += 64) {
    const int row = flaglist[f];
    double part[10];
#pragma unroll
    for (int i = 0; i < 10; ++i) part[i] = 0.0;
    for (int j = t; j < HD; j += 256) {
      double hj = (double)z32[(size_t)f * HD + j] + (double)encB[j];
      hj = hj > 0.0 ? hj : 0.0;
      const float* gr = gW + (size_t)j * 8;
#pragma unroll
      for (int e2 = 0; e2 < 8; ++e2) part[e2] += hj * (double)gr[e2];
      part[8] += hj * (double)cW[j * 2];
      part[9] += hj * (double)cW[j * 2 + 1];
    }
#pragma unroll
    for (int off = 32; off > 0; off >>= 1)
#pragma unroll
      for (int i = 0; i < 10; ++i) part[i] += __shfl_xor(part[i], off);
    if (lane == 0)
#pragma unroll
      for (int i = 0; i < 10; ++i) red[w][i] = part[i];
    __syncthreads();
    if (t == 0) {
      double a[10];
#pragma unroll
      for (int i = 0; i < 10; ++i)
        a[i] = red[0][i] + red[1][i] + red[2][i] + red[3][i];
      int best = 0; double bm = a[0];
#pragma unroll
      for (int e2 = 1; e2 < 8; ++e2) if (a[e2] > bm) { bm = a[e2]; best = e2; }
      double s = 0.0;
#pragma unroll
      for (int e2 = 0; e2 < 8; ++e2) s += exp(a[e2] - bm);
      const double p  = 1.0 / s;
      const double l0 = a[8] + (double)cb[0], l1 = a[9] + (double)cb[1];
      const double mx = l0 > l1 ? l0 : l1;
      const double e0 = exp(l0 - mx), e1 = exp(l1 - mx);
      const double inv = 1.0 / (e0 + e1);
      eidx[row] = best;
      s0[row]   = (float)(p * e0 * inv);
      c1[row]   = (float)(e1 * inv);
    }
    __syncthreads();
  }
}

__global__ __launch_bounds__(256)
void count_kernel(const int* __restrict__ eidx, unsigned* __restrict__ cnt) {
  const int n = blockIdx.x * 256 + threadIdx.x;
  atomicAdd(&cnt[eidx[n]], 1u);
}

__global__ void scan_kernel(const unsigned* __restrict__ cnt,
                            int* __restrict__ tinfo, int* __restrict__ offs,
                            int* __restrict__ cursor) {
  if (threadIdx.x == 0 && blockIdx.x == 0) {
    int off = 0, nt = 0;
    for (int e = 0; e < NEXP; ++e) {
      offs[e] = off; cursor[e] = 0;
      const int c = (int)cnt[e];
      const int end = off + c;
      for (int r = 0; r < c; r += 128) {
        tinfo[1 + nt * 3 + 0] = e;
        tinfo[1 + nt * 3 + 1] = off + r;
        tinfo[1 + nt * 3 + 2] = end;
        ++nt;
      }
      off = end;
    }
    tinfo[0] = nt;
  }
}

__global__ __launch_bounds__(256)
void scatter_kernel(const int* __restrict__ eidx, const int* __restrict__ offs,
                    int* __restrict__ cursor, int* __restrict__ rowperm) {
  const int n = blockIdx.x * 256 + threadIdx.x;
  const int e = eidx[n];
  rowperm[offs[e] + atomicAdd(&cursor[e], 1)] = n;
}

// ----------------------------------------------------------------------------
extern "C" void kernel_launch(void* const* d_in, const int* in_sizes, int n_in,
                              void* d_out, int out_size, void* d_ws, size_t ws_size,
                              hipStream_t stream) {
  (void)in_sizes; (void)n_in; (void)out_size;
  const float* x      = (const float*)d_in[0];
  const float* enc_W  = (const float*)d_in[1];
  const float* enc_b  = (const float*)d_in[2];
  const float* gate_W = (const float*)d_in[3];
  const float* exp_W  = (const float*)d_in[4];
  const float* exp_b  = (const float*)d_in[5];
  const float* mlp_W  = (const float*)d_in[6];
  const float* mlp_b  = (const float*)d_in[7];
  const float* coef_W = (const float*)d_in[8];
  const float* coef_b = (const float*)d_in[9];
  const float* dec_W  = (const float*)d_in[10];
  const float* dec_b  = (const float*)d_in[11];

  char* ws = (char*)d_ws;
  size_t off = 0;
  auto alloc = [&](size_t bytes) {
    char* p = ws + off;
    off += (bytes + 255) & ~(size_t)255;
    return p;
  };
  uint16_t* encWT  = (uint16_t*)alloc((size_t)DIN * HD * 2);         //  4 MiB
  uint16_t* mlpWT  = (uint16_t*)alloc((size_t)HD * HD * 2);          //  2 MiB
  uint16_t* decWT  = (uint16_t*)alloc((size_t)HD * DIN * 2);         //  4 MiB
  uint16_t* expWT  = (uint16_t*)alloc((size_t)NEXP * HD * HD * 2);   // 16 MiB
  uint16_t* h_bf   = (uint16_t*)alloc((size_t)NROWS * HD * 2);       // 16 MiB
  float*    h32    = (float*)   alloc((size_t)NROWS * HD * 4);       // 32 MiB
  float*    z32    = (float*)   alloc((size_t)MAXFLAG * HD * 4);     //  2 MiB
  int*      eidx   = (int*)     alloc(NROWS * 4);
  float*    s0     = (float*)   alloc(NROWS * 4);
  float*    c1     = (float*)   alloc(NROWS * 4);
  int*      rowperm= (int*)     alloc(NROWS * 4);
  int*      flags  = (int*)     alloc(MAXFLAG * 4);
  char*     ctrs   = (char*)    alloc(256);
  int*      offs   = (int*)     alloc(64);
  int*      cursor = (int*)     alloc(64);
  int*      tinfo  = (int*)     alloc((1 + MAX_TILES * 3) * 4 + 64);
  // accout aliases h32 (h32 dead after gate/fixup; expert GEMM runs later)
  uint16_t* accout = (uint16_t*)h32;
  unsigned* cnt    = (unsigned*)ctrs;
  int*      nflag  = (int*)(ctrs + 32);
  if (off > ws_size) return;

  hipMemsetAsync(ctrs, 0, 256, stream);

  const dim3 blk(256);
  tcast_k<<<dim3(HD / 64, DIN / 64, 1),    blk, 0, stream>>>(enc_W, encWT, DIN, HD);
  tcast_k<<<dim3(HD / 64, HD / 64, 1),     blk, 0, stream>>>(mlp_W, mlpWT, HD, HD);
  tcast_k<<<dim3(DIN / 64, HD / 64, 1),    blk, 0, stream>>>(dec_W, decWT, HD, DIN);
  tcast_k<<<dim3(HD / 64, HD / 64, NEXP),  blk, 0, stream>>>(exp_W, expWT, HD, HD);

  gemm_kernel<0><<<dim3(NROWS / 128, HD / 128), blk, 0, stream>>>(
      x, encWT, h_bf, nullptr, enc_b, h32, nullptr, nullptr, nullptr,
      NROWS, HD, DIN);

  gate_kernel<<<dim3(NROWS / 4), blk, 0, stream>>>(
      h32, gate_W, coef_W, coef_b, eidx, s0, c1, nflag, flags);
  fixup1_kernel<<<dim3(HD / 4), blk, 0, stream>>>(x, enc_W, flags, nflag, z32);
  fixup2_kernel<<<dim3(64), blk, 0, stream>>>(
      z32, enc_b, gate_W, coef_W, coef_b, flags, nflag, eidx, s0, c1);

  count_kernel<<<dim3(NROWS / 256), blk, 0, stream>>>(eidx, cnt);
  scan_kernel<<<1, 64, 0, stream>>>(cnt, tinfo, offs, cursor);
  scatter_kernel<<<dim3(NROWS / 256), blk, 0, stream>>>(eidx, offs, cursor, rowperm);

  gemm_kernel<1><<<dim3(MAX_TILES, HD / 128), blk, 0, stream>>>(
      h_bf, expWT, accout, nullptr, exp_b, nullptr, rowperm, tinfo, s0,
      NROWS, HD, HD);
  gemm_kernel<2><<<dim3(NROWS / 128, HD / 128), blk, 0, stream>>>(
      h_bf, mlpWT, accout, nullptr, mlp_b, nullptr, nullptr, nullptr, c1,
      NROWS, HD, HD);
  gemm_kernel<3><<<dim3(NROWS / 128, DIN / 128), blk, 0, stream>>>(
      accout, decWT, nullptr, (float*)d_out, dec_b, nullptr, nullptr, nullptr,
      nullptr, NROWS, DIN, HD);
}

// Round 4
// 701.747 us; speedup vs baseline: 1.1064x; 1.1064x over previous
//
#include <hip/hip_runtime.h>
#include <hip/hip_bf16.h>
#include <stdint.h>

// ============================================================================
// MoE Autoencoder (N=8192, D_IN=2048, H=1024, E=8).  f32 in / f32 out,
// bf16-tolerance (0.0625) => bf16 MFMA compute.
// Round 4 (= Round 3 with the MODE-1 launch arg-count fixed):
//   - fixup1: reg-resident enc_W slab, k-split, LDS reduce, deterministic
//     partial buffer (no float atomics).  417us -> ~15us predicted.
//   - h32 dropped; gate reads bf16 h (GAPTHR=0.02 ~ 10 sigma of bf16 noise)
//   - accout aliases zpart (dead after fixup2)
// ============================================================================

using bf16 = __hip_bfloat16;
typedef __bf16 bf16x8 __attribute__((ext_vector_type(8)));
typedef float f32x4 __attribute__((ext_vector_type(4)));

static constexpr int NROWS = 8192;
static constexpr int DIN   = 2048;
static constexpr int HD    = 1024;
static constexpr int NEXP  = 8;
static constexpr int MAX_TILES = 72;     // sum_e ceil(cnt_e/128) <= 64+7
static constexpr int MAXFLAG = 512;
#define GAPTHR 0.02f

__device__ __forceinline__ uint16_t f2u(float f) {
  bf16 h = __float2bfloat16(f);
  uint16_t u; __builtin_memcpy(&u, &h, 2); return u;
}
__device__ __forceinline__ float u2f(uint16_t u) {
  uint32_t x = ((uint32_t)u) << 16;
  float f; __builtin_memcpy(&f, &x, 4); return f;
}

typedef const __attribute__((address_space(1))) void* gas_ptr;
typedef __attribute__((address_space(3))) void* las_ptr;
__device__ __forceinline__ void async16(void* lds, const void* g) {
  __builtin_amdgcn_global_load_lds((gas_ptr)g, (las_ptr)lds, 16, 0, 0);
}

// ----------------------------------------------------------------------------
// 64x64-tile transpose + cast f32 -> bf16: out[C][R] = bf16(in[R][C]).
// ----------------------------------------------------------------------------
__global__ __launch_bounds__(256)
void tcast_k(const float* __restrict__ in, uint16_t* __restrict__ out,
             int R, int C) {
  __shared__ float tile[64 * 65];
  const int t  = threadIdx.x;
  const int C0 = blockIdx.x * 64, R0 = blockIdx.y * 64;
  in  += (size_t)blockIdx.z * R * C;
  out += (size_t)blockIdx.z * R * C;
  const int cl = (t & 7) * 8;
#pragma unroll
  for (int p = 0; p < 2; ++p) {
    const int r = p * 32 + (t >> 3);
    const float* src = in + (size_t)(R0 + r) * C + C0 + cl;
    float4 v0 = *(const float4*)(src);
    float4 v1 = *(const float4*)(src + 4);
    float* dst = &tile[r * 65 + cl];
    dst[0] = v0.x; dst[1] = v0.y; dst[2] = v0.z; dst[3] = v0.w;
    dst[4] = v1.x; dst[5] = v1.y; dst[6] = v1.z; dst[7] = v1.w;
  }
  __syncthreads();
#pragma unroll
  for (int p = 0; p < 2; ++p) {
    const int oc = p * 32 + (t >> 3);
    uint16_t tmp[8];
#pragma unroll
    for (int j = 0; j < 8; ++j) tmp[j] = f2u(tile[(cl + j) * 65 + oc]);
    int4 v; __builtin_memcpy(&v, tmp, 16);
    *(int4*)(out + (size_t)(C0 + oc) * R + R0 + cl) = v;
  }
}

// ----------------------------------------------------------------------------
// 128x128-tile GEMM, BK=64, 4 waves:  C = epilogue(A[M,K] @ BT[N,K]^T)
// MODE 0: enc  — A is f32 (reg-stage cast); relu(acc+b) -> C16 (bf16)
// MODE 1: exp  — gathered rows; (acc + b_e) * scale[orig], scattered (bf16)
// MODE 2: mlp  — C16[r,c] += (acc + b) * scale[r]         (bf16 RMW)
// MODE 3: dec  — C32 = acc + b                            (f32 out)
// ----------------------------------------------------------------------------
template<int MODE>
__global__ __launch_bounds__(256)
void gemm_kernel(const void* __restrict__ Av, const uint16_t* __restrict__ BT,
                 uint16_t* __restrict__ C16, float* __restrict__ C32,
                 const float* __restrict__ biasf,
                 const int* __restrict__ rowperm, const int* __restrict__ tinfo,
                 const float* __restrict__ scale, int M, int N, int K)
{
  const int t = threadIdx.x;
  const int mtile = blockIdx.x, ntile = blockIdx.y;

  int e = 0, row0 = 0, rowend = 0;
  if constexpr (MODE == 1) {
    const int nt = tinfo[0];
    if (mtile >= nt) return;
    e      = tinfo[1 + mtile * 3 + 0];
    row0   = tinfo[1 + mtile * 3 + 1];
    rowend = tinfo[1 + mtile * 3 + 2];
  }

  __shared__ uint16_t As[128 * 64];
  __shared__ uint16_t Bs[128 * 64];

  const int kcol = (t & 7) * 8;
  const char* asrc[4];
  const uint16_t* bsrc[4];
  const int aelt = (MODE == 0) ? 4 : 2;
#pragma unroll
  for (int c = 0; c < 4; ++c) {
    const int r = c * 32 + (t >> 3);
    int arow;
    if constexpr (MODE == 1) {
      int pr = row0 + r;
      if (pr > rowend - 1) pr = rowend - 1;     // pad rows clamped, masked later
      arow = rowperm[pr];
    } else {
      arow = mtile * 128 + r;
    }
    asrc[c] = (const char*)Av + ((size_t)arow * K + kcol) * aelt;
    size_t brow = (size_t)ntile * 128 + r;
    if constexpr (MODE == 1) brow += (size_t)e * N;   // expWT: [E][N][K]
    bsrc[c] = BT + brow * (size_t)K + kcol;
  }

  f32x4 acc[4][4];
  const f32x4 zero = {0.f, 0.f, 0.f, 0.f};
#pragma unroll
  for (int i = 0; i < 4; ++i)
#pragma unroll
    for (int j = 0; j < 4; ++j) acc[i][j] = zero;

  const int wid = t >> 6, lane = t & 63;
  const int wm = wid >> 1, wn = wid & 1;
  const int frow = lane & 15;
  const int fk = (lane >> 4) * 8;

  const int nk = K >> 6;
  for (int kt = 0; kt < nk; ++kt) {
    if constexpr (MODE == 0) {
#pragma unroll
      for (int c = 0; c < 4; ++c) {
        const float* s = (const float*)asrc[c] + kt * 64;
        float4 v0 = *(const float4*)(s);
        float4 v1 = *(const float4*)(s + 4);
        uint16_t tmp[8];
        tmp[0] = f2u(v0.x); tmp[1] = f2u(v0.y); tmp[2] = f2u(v0.z); tmp[3] = f2u(v0.w);
        tmp[4] = f2u(v1.x); tmp[5] = f2u(v1.y); tmp[6] = f2u(v1.z); tmp[7] = f2u(v1.w);
        int4 pv; __builtin_memcpy(&pv, tmp, 16);
        *(int4*)&As[c * 2048 + t * 8] = pv;
      }
#pragma unroll
      for (int c = 0; c < 4; ++c)
        async16(&Bs[c * 2048 + t * 8], bsrc[c] + kt * 64);
    } else {
#pragma unroll
      for (int c = 0; c < 4; ++c) {
        async16(&As[c * 2048 + t * 8], (const uint16_t*)asrc[c] + kt * 64);
        async16(&Bs[c * 2048 + t * 8], bsrc[c] + kt * 64);
      }
    }
    __syncthreads();
#pragma unroll
    for (int kk = 0; kk < 2; ++kk) {
      bf16x8 af[4], bfr[4];
#pragma unroll
      for (int mi = 0; mi < 4; ++mi)
        af[mi] = *reinterpret_cast<const bf16x8*>(
            &As[(wm * 64 + mi * 16 + frow) * 64 + kk * 32 + fk]);
#pragma unroll
      for (int ni = 0; ni < 4; ++ni)
        bfr[ni] = *reinterpret_cast<const bf16x8*>(
            &Bs[(wn * 64 + ni * 16 + frow) * 64 + kk * 32 + fk]);
#pragma unroll
      for (int mi = 0; mi < 4; ++mi)
#pragma unroll
        for (int ni = 0; ni < 4; ++ni)
          acc[mi][ni] = __builtin_amdgcn_mfma_f32_16x16x32_bf16(
              af[mi], bfr[ni], acc[mi][ni], 0, 0, 0);
    }
    __syncthreads();
  }

  // epilogue — C/D layout: col = lane&15, row = (lane>>4)*4 + j   [m89]
  const int nbase = ntile * 128 + wn * 64;
  const int rbase = wm * 64 + (lane >> 4) * 4;
  const int cbase = lane & 15;
#pragma unroll
  for (int mi = 0; mi < 4; ++mi) {
#pragma unroll
    for (int j = 0; j < 4; ++j) {
      const int rr = rbase + mi * 16 + j;
      if constexpr (MODE == 1) {
        const int pr = row0 + rr;
        if (pr < rowend) {
          const int orig = rowperm[pr];
          const float sc = scale[orig];
          uint16_t* dst = C16 + (size_t)orig * N;
#pragma unroll
          for (int ni = 0; ni < 4; ++ni) {
            const int gc = nbase + ni * 16 + cbase;
            dst[gc] = f2u((acc[mi][ni][j] + biasf[e * N + gc]) * sc);
          }
        }
      } else {
        const int gr = mtile * 128 + rr;
#pragma unroll
        for (int ni = 0; ni < 4; ++ni) {
          const int gc = nbase + ni * 16 + cbase;
          float v = acc[mi][ni][j] + biasf[gc];
          if constexpr (MODE == 0) {
            C16[(size_t)gr * N + gc] = f2u(fmaxf(v, 0.f));
          } else if constexpr (MODE == 2) {
            const float prev = u2f(C16[(size_t)gr * N + gc]);
            C16[(size_t)gr * N + gc] = f2u(prev + v * scale[gr]);
          } else {
            C32[(size_t)gr * N + gc] = v;
          }
        }
      }
    }
  }
}

// ----------------------------------------------------------------------------
// Gate from bf16 h: logits = h @ gate_W, coef = softmax(h @ coef_W + cb).
// One wave per row; flags rows with top2 gap < GAPTHR for exact fixup.
// ----------------------------------------------------------------------------
__global__ __launch_bounds__(256)
void gate_kernel(const uint16_t* __restrict__ hbf, const float* __restrict__ gW,
                 const float* __restrict__ cW, const float* __restrict__ cb,
                 int* __restrict__ eidx, float* __restrict__ s0,
                 float* __restrict__ c1, int* __restrict__ nflag,
                 int* __restrict__ flaglist)
{
  const int lane = threadIdx.x & 63;
  const int row  = blockIdx.x * 4 + (threadIdx.x >> 6);
  const uint16_t* hrow = hbf + (size_t)row * HD;
  float a[10];
#pragma unroll
  for (int i = 0; i < 10; ++i) a[i] = 0.f;
  for (int kk = 0; kk < HD / 64; ++kk) {
    const int k = kk * 64 + lane;
    const float hv = u2f(hrow[k]);
    float4 g0 = *(const float4*)(gW + (size_t)k * 8);
    float4 g1 = *(const float4*)(gW + (size_t)k * 8 + 4);
    a[0] += hv * g0.x; a[1] += hv * g0.y; a[2] += hv * g0.z; a[3] += hv * g0.w;
    a[4] += hv * g1.x; a[5] += hv * g1.y; a[6] += hv * g1.z; a[7] += hv * g1.w;
    float2 cv = *(const float2*)(cW + (size_t)k * 2);
    a[8] += hv * cv.x; a[9] += hv * cv.y;
  }
#pragma unroll
  for (int off = 32; off > 0; off >>= 1) {
#pragma unroll
    for (int i = 0; i < 10; ++i) a[i] += __shfl_xor(a[i], off);
  }
  if (lane == 0) {
    int best = 0; float bm = a[0];
#pragma unroll
    for (int e2 = 1; e2 < 8; ++e2) if (a[e2] > bm) { bm = a[e2]; best = e2; }
    float sec = -3.0e38f;
#pragma unroll
    for (int e2 = 0; e2 < 8; ++e2) if (e2 != best) sec = fmaxf(sec, a[e2]);
    float s = 0.f;
#pragma unroll
    for (int e2 = 0; e2 < 8; ++e2) s += expf(a[e2] - bm);
    const float p  = 1.f / s;
    const float l0 = a[8] + cb[0], l1 = a[9] + cb[1];
    const float mx = fmaxf(l0, l1);
    const float e0 = expf(l0 - mx), e1 = expf(l1 - mx);
    const float inv = 1.f / (e0 + e1);
    eidx[row] = best;
    s0[row]   = p * (e0 * inv);
    c1[row]   = e1 * inv;
    if (bm - sec < GAPTHR) {
      int fi = atomicAdd(nflag, 1);
      if (fi < MAXFLAG) flaglist[fi] = row;
    }
  }
}

// ----------------------------------------------------------------------------
// fixup1: zpart[kb][f][j] = sum_{k in chunk kb} x[row_f][k] * enc_W[k][j]
// grid (HD/64, 8).  enc_W slab held in registers (read once, coalesced);
// x chunk broadcast from LDS; f64 accum; deterministic (no atomics).
// ----------------------------------------------------------------------------
__global__ __launch_bounds__(256)
void fixup1_kernel(const float* __restrict__ x, const float* __restrict__ encW,
                   const int* __restrict__ flaglist, const int* __restrict__ nflag,
                   float* __restrict__ zpart)   // [8][MAXFLAG][HD]
{
  __shared__ float xs[256];
  __shared__ float red[4][64];
  int nf = *nflag; if (nf > MAXFLAG) nf = MAXFLAG;
  const int t  = threadIdx.x;
  const int jb = blockIdx.x, kb = blockIdx.y;
  const int tj = t & 63, tk = t >> 6;
  const int j  = jb * 64 + tj;
  const int k0 = kb * 256 + tk * 64;
  float w[64];
#pragma unroll
  for (int kk = 0; kk < 64; ++kk)
    w[kk] = encW[(size_t)(k0 + kk) * HD + j];
  for (int f = 0; f < nf; ++f) {
    const int row = flaglist[f];
    __syncthreads();                      // protect xs/red from previous iter
    xs[t] = x[(size_t)row * DIN + kb * 256 + t];
    __syncthreads();
    const float* xc = &xs[tk * 64];
    double a0 = 0, a1 = 0, a2 = 0, a3 = 0;
#pragma unroll
    for (int kk = 0; kk < 64; kk += 4) {
      a0 += (double)xc[kk]     * (double)w[kk];
      a1 += (double)xc[kk + 1] * (double)w[kk + 1];
      a2 += (double)xc[kk + 2] * (double)w[kk + 2];
      a3 += (double)xc[kk + 3] * (double)w[kk + 3];
    }
    red[tk][tj] = (float)((a0 + a1) + (a2 + a3));
    __syncthreads();
    if (t < 64)
      zpart[((size_t)kb * MAXFLAG + f) * HD + jb * 64 + t]
          = (red[0][t] + red[1][t]) + (red[2][t] + red[3][t]);
  }
}

// ----------------------------------------------------------------------------
// fixup2: exact gate for flagged rows; overwrites eidx/s0/c1.
// ----------------------------------------------------------------------------
__global__ __launch_bounds__(256)
void fixup2_kernel(const float* __restrict__ zpart, const float* __restrict__ encB,
                   const float* __restrict__ gW, const float* __restrict__ cW,
                   const float* __restrict__ cb, const int* __restrict__ flaglist,
                   const int* __restrict__ nflag, int* __restrict__ eidx,
                   float* __restrict__ s0, float* __restrict__ c1)
{
  __shared__ double red[4][10];
  int nf = *nflag; if (nf > MAXFLAG) nf = MAXFLAG;
  const int t = threadIdx.x, lane = t & 63, w = t >> 6;
  for (int f = blockIdx.x; f < nf; f += 64) {
    const int row = flaglist[f];
    double part[10];
#pragma unroll
    for (int i = 0; i < 10; ++i) part[i] = 0.0;
    for (int jj = t; jj < HD; jj += 256) {
      double z = 0.0;
#pragma unroll
      for (int kb = 0; kb < 8; ++kb)
        z += (double)zpart[((size_t)kb * MAXFLAG + f) * HD + jj];
      double hj = z + (double)encB[jj];
      hj = hj > 0.0 ? hj : 0.0;
      const float* gr = gW + (size_t)jj * 8;
#pragma unroll
      for (int e2 = 0; e2 < 8; ++e2) part[e2] += hj * (double)gr[e2];
      part[8] += hj * (double)cW[jj * 2];
      part[9] += hj * (double)cW[jj * 2 + 1];
    }
#pragma unroll
    for (int off = 32; off > 0; off >>= 1)
#pragma unroll
      for (int i = 0; i < 10; ++i) part[i] += __shfl_xor(part[i], off);
    if (lane == 0)
#pragma unroll
      for (int i = 0; i < 10; ++i) red[w][i] = part[i];
    __syncthreads();
    if (t == 0) {
      double a[10];
#pragma unroll
      for (int i = 0; i < 10; ++i)
        a[i] = red[0][i] + red[1][i] + red[2][i] + red[3][i];
      int best = 0; double bm = a[0];
#pragma unroll
      for (int e2 = 1; e2 < 8; ++e2) if (a[e2] > bm) { bm = a[e2]; best = e2; }
      double s = 0.0;
#pragma unroll
      for (int e2 = 0; e2 < 8; ++e2) s += exp(a[e2] - bm);
      const double p  = 1.0 / s;
      const double l0 = a[8] + (double)cb[0], l1 = a[9] + (double)cb[1];
      const double mx = l0 > l1 ? l0 : l1;
      const double e0 = exp(l0 - mx), e1 = exp(l1 - mx);
      const double inv = 1.0 / (e0 + e1);
      eidx[row] = best;
      s0[row]   = (float)(p * e0 * inv);
      c1[row]   = (float)(e1 * inv);
    }
    __syncthreads();
  }
}

__global__ __launch_bounds__(256)
void count_kernel(const int* __restrict__ eidx, unsigned* __restrict__ cnt) {
  const int n = blockIdx.x * 256 + threadIdx.x;
  atomicAdd(&cnt[eidx[n]], 1u);
}

__global__ void scan_kernel(const unsigned* __restrict__ cnt,
                            int* __restrict__ tinfo, int* __restrict__ offs,
                            int* __restrict__ cursor) {
  if (threadIdx.x == 0 && blockIdx.x == 0) {
    int off = 0, nt = 0;
    for (int e = 0; e < NEXP; ++e) {
      offs[e] = off; cursor[e] = 0;
      const int c = (int)cnt[e];
      const int end = off + c;
      for (int r = 0; r < c; r += 128) {
        tinfo[1 + nt * 3 + 0] = e;
        tinfo[1 + nt * 3 + 1] = off + r;
        tinfo[1 + nt * 3 + 2] = end;
        ++nt;
      }
      off = end;
    }
    tinfo[0] = nt;
  }
}

__global__ __launch_bounds__(256)
void scatter_kernel(const int* __restrict__ eidx, const int* __restrict__ offs,
                    int* __restrict__ cursor, int* __restrict__ rowperm) {
  const int n = blockIdx.x * 256 + threadIdx.x;
  const int e = eidx[n];
  rowperm[offs[e] + atomicAdd(&cursor[e], 1)] = n;
}

// ----------------------------------------------------------------------------
extern "C" void kernel_launch(void* const* d_in, const int* in_sizes, int n_in,
                              void* d_out, int out_size, void* d_ws, size_t ws_size,
                              hipStream_t stream) {
  (void)in_sizes; (void)n_in; (void)out_size;
  const float* x      = (const float*)d_in[0];
  const float* enc_W  = (const float*)d_in[1];
  const float* enc_b  = (const float*)d_in[2];
  const float* gate_W = (const float*)d_in[3];
  const float* exp_W  = (const float*)d_in[4];
  const float* exp_b  = (const float*)d_in[5];
  const float* mlp_W  = (const float*)d_in[6];
  const float* mlp_b  = (const float*)d_in[7];
  const float* coef_W = (const float*)d_in[8];
  const float* coef_b = (const float*)d_in[9];
  const float* dec_W  = (const float*)d_in[10];
  const float* dec_b  = (const float*)d_in[11];

  char* ws = (char*)d_ws;
  size_t off = 0;
  auto alloc = [&](size_t bytes) {
    char* p = ws + off;
    off += (bytes + 255) & ~(size_t)255;
    return p;
  };
  uint16_t* encWT  = (uint16_t*)alloc((size_t)DIN * HD * 2);         //  4 MiB
  uint16_t* mlpWT  = (uint16_t*)alloc((size_t)HD * HD * 2);          //  2 MiB
  uint16_t* decWT  = (uint16_t*)alloc((size_t)HD * DIN * 2);         //  4 MiB
  uint16_t* expWT  = (uint16_t*)alloc((size_t)NEXP * HD * HD * 2);   // 16 MiB
  uint16_t* h_bf   = (uint16_t*)alloc((size_t)NROWS * HD * 2);       // 16 MiB
  float*    zpart  = (float*)   alloc((size_t)8 * MAXFLAG * HD * 4); // 16 MiB
  int*      eidx   = (int*)     alloc(NROWS * 4);
  float*    s0     = (float*)   alloc(NROWS * 4);
  float*    c1     = (float*)   alloc(NROWS * 4);
  int*      rowperm= (int*)     alloc(NROWS * 4);
  int*      flags  = (int*)     alloc(MAXFLAG * 4);
  char*     ctrs   = (char*)    alloc(256);
  int*      offs   = (int*)     alloc(64);
  int*      cursor = (int*)     alloc(64);
  int*      tinfo  = (int*)     alloc((1 + MAX_TILES * 3) * 4 + 64);
  // accout aliases zpart: zpart is dead after fixup2; expert GEMM then writes
  // every element of accout before mlp/dec read it.
  uint16_t* accout = (uint16_t*)zpart;
  unsigned* cnt    = (unsigned*)ctrs;
  int*      nflag  = (int*)(ctrs + 32);
  if (off > ws_size) return;

  hipMemsetAsync(ctrs, 0, 256, stream);

  const dim3 blk(256);
  tcast_k<<<dim3(HD / 64, DIN / 64, 1),    blk, 0, stream>>>(enc_W, encWT, DIN, HD);
  tcast_k<<<dim3(HD / 64, HD / 64, 1),     blk, 0, stream>>>(mlp_W, mlpWT, HD, HD);
  tcast_k<<<dim3(DIN / 64, HD / 64, 1),    blk, 0, stream>>>(dec_W, decWT, HD, DIN);
  tcast_k<<<dim3(HD / 64, HD / 64, NEXP),  blk, 0, stream>>>(exp_W, expWT, HD, HD);

  gemm_kernel<0><<<dim3(NROWS / 128, HD / 128), blk, 0, stream>>>(
      x, encWT, h_bf, nullptr, enc_b, nullptr, nullptr, nullptr,
      NROWS, HD, DIN);

  gate_kernel<<<dim3(NROWS / 4), blk, 0, stream>>>(
      h_bf, gate_W, coef_W, coef_b, eidx, s0, c1, nflag, flags);
  fixup1_kernel<<<dim3(HD / 64, 8), blk, 0, stream>>>(x, enc_W, flags, nflag, zpart);
  fixup2_kernel<<<dim3(64), blk, 0, stream>>>(
      zpart, enc_b, gate_W, coef_W, coef_b, flags, nflag, eidx, s0, c1);

  count_kernel<<<dim3(NROWS / 256), blk, 0, stream>>>(eidx, cnt);
  scan_kernel<<<1, 64, 0, stream>>>(cnt, tinfo, offs, cursor);
  scatter_kernel<<<dim3(NROWS / 256), blk, 0, stream>>>(eidx, offs, cursor, rowperm);

  gemm_kernel<1><<<dim3(MAX_TILES, HD / 128), blk, 0, stream>>>(
      h_bf, expWT, accout, nullptr, exp_b, rowperm, tinfo, s0,
      NROWS, HD, HD);
  gemm_kernel<2><<<dim3(NROWS / 128, HD / 128), blk, 0, stream>>>(
      h_bf, mlpWT, accout, nullptr, mlp_b, nullptr, nullptr, c1,
      NROWS, HD, HD);
  gemm_kernel<3><<<dim3(NROWS / 128, DIN / 128), blk, 0, stream>>>(
      accout, decWT, nullptr, (float*)d_out, dec_b, nullptr, nullptr, nullptr,
      NROWS, DIN, HD);
}

// Round 5
// 486.877 us; speedup vs baseline: 1.5946x; 1.4413x over previous
//
#include <hip/hip_runtime.h>
#include <hip/hip_bf16.h>
#include <stdint.h>

// ============================================================================
// MoE Autoencoder (N=8192, D_IN=2048, H=1024, E=8).  f32 in / f32 out,
// bf16-tolerance (0.0625) => bf16 MFMA compute.
// Round 5: fixup1 de-serialized.
//   - grid (16 jb, 16 kb) = 256 blocks, disjoint W slabs (traffic-optimal)
//   - row-batch R=8: 1 barrier pair / 8 rows, 8 indep f64 chains, full-block
//     stores.  349us -> ~35us predicted.
//   - fixup2: 16 k-partials, 128 blocks.
// ============================================================================

using bf16 = __hip_bfloat16;
typedef __bf16 bf16x8 __attribute__((ext_vector_type(8)));
typedef float f32x4 __attribute__((ext_vector_type(4)));

static constexpr int NROWS = 8192;
static constexpr int DIN   = 2048;
static constexpr int HD    = 1024;
static constexpr int NEXP  = 8;
static constexpr int MAX_TILES = 72;     // sum_e ceil(cnt_e/128) <= 64+7
static constexpr int MAXFLAG = 512;      // measured nf ~ 345
#define GAPTHR 0.02f

__device__ __forceinline__ uint16_t f2u(float f) {
  bf16 h = __float2bfloat16(f);
  uint16_t u; __builtin_memcpy(&u, &h, 2); return u;
}
__device__ __forceinline__ float u2f(uint16_t u) {
  uint32_t x = ((uint32_t)u) << 16;
  float f; __builtin_memcpy(&f, &x, 4); return f;
}

typedef const __attribute__((address_space(1))) void* gas_ptr;
typedef __attribute__((address_space(3))) void* las_ptr;
__device__ __forceinline__ void async16(void* lds, const void* g) {
  __builtin_amdgcn_global_load_lds((gas_ptr)g, (las_ptr)lds, 16, 0, 0);
}

// ----------------------------------------------------------------------------
// 64x64-tile transpose + cast f32 -> bf16: out[C][R] = bf16(in[R][C]).
// ----------------------------------------------------------------------------
__global__ __launch_bounds__(256)
void tcast_k(const float* __restrict__ in, uint16_t* __restrict__ out,
             int R, int C) {
  __shared__ float tile[64 * 65];
  const int t  = threadIdx.x;
  const int C0 = blockIdx.x * 64, R0 = blockIdx.y * 64;
  in  += (size_t)blockIdx.z * R * C;
  out += (size_t)blockIdx.z * R * C;
  const int cl = (t & 7) * 8;
#pragma unroll
  for (int p = 0; p < 2; ++p) {
    const int r = p * 32 + (t >> 3);
    const float* src = in + (size_t)(R0 + r) * C + C0 + cl;
    float4 v0 = *(const float4*)(src);
    float4 v1 = *(const float4*)(src + 4);
    float* dst = &tile[r * 65 + cl];
    dst[0] = v0.x; dst[1] = v0.y; dst[2] = v0.z; dst[3] = v0.w;
    dst[4] = v1.x; dst[5] = v1.y; dst[6] = v1.z; dst[7] = v1.w;
  }
  __syncthreads();
#pragma unroll
  for (int p = 0; p < 2; ++p) {
    const int oc = p * 32 + (t >> 3);
    uint16_t tmp[8];
#pragma unroll
    for (int j = 0; j < 8; ++j) tmp[j] = f2u(tile[(cl + j) * 65 + oc]);
    int4 v; __builtin_memcpy(&v, tmp, 16);
    *(int4*)(out + (size_t)(C0 + oc) * R + R0 + cl) = v;
  }
}

// ----------------------------------------------------------------------------
// 128x128-tile GEMM, BK=64, 4 waves:  C = epilogue(A[M,K] @ BT[N,K]^T)
// MODE 0: enc  — A is f32 (reg-stage cast); relu(acc+b) -> C16 (bf16)
// MODE 1: exp  — gathered rows; (acc + b_e) * scale[orig], scattered (bf16)
// MODE 2: mlp  — C16[r,c] += (acc + b) * scale[r]         (bf16 RMW)
// MODE 3: dec  — C32 = acc + b                            (f32 out)
// ----------------------------------------------------------------------------
template<int MODE>
__global__ __launch_bounds__(256)
void gemm_kernel(const void* __restrict__ Av, const uint16_t* __restrict__ BT,
                 uint16_t* __restrict__ C16, float* __restrict__ C32,
                 const float* __restrict__ biasf,
                 const int* __restrict__ rowperm, const int* __restrict__ tinfo,
                 const float* __restrict__ scale, int M, int N, int K)
{
  const int t = threadIdx.x;
  const int mtile = blockIdx.x, ntile = blockIdx.y;

  int e = 0, row0 = 0, rowend = 0;
  if constexpr (MODE == 1) {
    const int nt = tinfo[0];
    if (mtile >= nt) return;
    e      = tinfo[1 + mtile * 3 + 0];
    row0   = tinfo[1 + mtile * 3 + 1];
    rowend = tinfo[1 + mtile * 3 + 2];
  }

  __shared__ uint16_t As[128 * 64];
  __shared__ uint16_t Bs[128 * 64];

  const int kcol = (t & 7) * 8;
  const char* asrc[4];
  const uint16_t* bsrc[4];
  const int aelt = (MODE == 0) ? 4 : 2;
#pragma unroll
  for (int c = 0; c < 4; ++c) {
    const int r = c * 32 + (t >> 3);
    int arow;
    if constexpr (MODE == 1) {
      int pr = row0 + r;
      if (pr > rowend - 1) pr = rowend - 1;     // pad rows clamped, masked later
      arow = rowperm[pr];
    } else {
      arow = mtile * 128 + r;
    }
    asrc[c] = (const char*)Av + ((size_t)arow * K + kcol) * aelt;
    size_t brow = (size_t)ntile * 128 + r;
    if constexpr (MODE == 1) brow += (size_t)e * N;   // expWT: [E][N][K]
    bsrc[c] = BT + brow * (size_t)K + kcol;
  }

  f32x4 acc[4][4];
  const f32x4 zero = {0.f, 0.f, 0.f, 0.f};
#pragma unroll
  for (int i = 0; i < 4; ++i)
#pragma unroll
    for (int j = 0; j < 4; ++j) acc[i][j] = zero;

  const int wid = t >> 6, lane = t & 63;
  const int wm = wid >> 1, wn = wid & 1;
  const int frow = lane & 15;
  const int fk = (lane >> 4) * 8;

  const int nk = K >> 6;
  for (int kt = 0; kt < nk; ++kt) {
    if constexpr (MODE == 0) {
#pragma unroll
      for (int c = 0; c < 4; ++c) {
        const float* s = (const float*)asrc[c] + kt * 64;
        float4 v0 = *(const float4*)(s);
        float4 v1 = *(const float4*)(s + 4);
        uint16_t tmp[8];
        tmp[0] = f2u(v0.x); tmp[1] = f2u(v0.y); tmp[2] = f2u(v0.z); tmp[3] = f2u(v0.w);
        tmp[4] = f2u(v1.x); tmp[5] = f2u(v1.y); tmp[6] = f2u(v1.z); tmp[7] = f2u(v1.w);
        int4 pv; __builtin_memcpy(&pv, tmp, 16);
        *(int4*)&As[c * 2048 + t * 8] = pv;
      }
#pragma unroll
      for (int c = 0; c < 4; ++c)
        async16(&Bs[c * 2048 + t * 8], bsrc[c] + kt * 64);
    } else {
#pragma unroll
      for (int c = 0; c < 4; ++c) {
        async16(&As[c * 2048 + t * 8], (const uint16_t*)asrc[c] + kt * 64);
        async16(&Bs[c * 2048 + t * 8], bsrc[c] + kt * 64);
      }
    }
    __syncthreads();
#pragma unroll
    for (int kk = 0; kk < 2; ++kk) {
      bf16x8 af[4], bfr[4];
#pragma unroll
      for (int mi = 0; mi < 4; ++mi)
        af[mi] = *reinterpret_cast<const bf16x8*>(
            &As[(wm * 64 + mi * 16 + frow) * 64 + kk * 32 + fk]);
#pragma unroll
      for (int ni = 0; ni < 4; ++ni)
        bfr[ni] = *reinterpret_cast<const bf16x8*>(
            &Bs[(wn * 64 + ni * 16 + frow) * 64 + kk * 32 + fk]);
#pragma unroll
      for (int mi = 0; mi < 4; ++mi)
#pragma unroll
        for (int ni = 0; ni < 4; ++ni)
          acc[mi][ni] = __builtin_amdgcn_mfma_f32_16x16x32_bf16(
              af[mi], bfr[ni], acc[mi][ni], 0, 0, 0);
    }
    __syncthreads();
  }

  // epilogue — C/D layout: col = lane&15, row = (lane>>4)*4 + j   [m89]
  const int nbase = ntile * 128 + wn * 64;
  const int rbase = wm * 64 + (lane >> 4) * 4;
  const int cbase = lane & 15;
#pragma unroll
  for (int mi = 0; mi < 4; ++mi) {
#pragma unroll
    for (int j = 0; j < 4; ++j) {
      const int rr = rbase + mi * 16 + j;
      if constexpr (MODE == 1) {
        const int pr = row0 + rr;
        if (pr < rowend) {
          const int orig = rowperm[pr];
          const float sc = scale[orig];
          uint16_t* dst = C16 + (size_t)orig * N;
#pragma unroll
          for (int ni = 0; ni < 4; ++ni) {
            const int gc = nbase + ni * 16 + cbase;
            dst[gc] = f2u((acc[mi][ni][j] + biasf[e * N + gc]) * sc);
          }
        }
      } else {
        const int gr = mtile * 128 + rr;
#pragma unroll
        for (int ni = 0; ni < 4; ++ni) {
          const int gc = nbase + ni * 16 + cbase;
          float v = acc[mi][ni][j] + biasf[gc];
          if constexpr (MODE == 0) {
            C16[(size_t)gr * N + gc] = f2u(fmaxf(v, 0.f));
          } else if constexpr (MODE == 2) {
            const float prev = u2f(C16[(size_t)gr * N + gc]);
            C16[(size_t)gr * N + gc] = f2u(prev + v * scale[gr]);
          } else {
            C32[(size_t)gr * N + gc] = v;
          }
        }
      }
    }
  }
}

// ----------------------------------------------------------------------------
// Gate from bf16 h: logits = h @ gate_W, coef = softmax(h @ coef_W + cb).
// One wave per row; flags rows with top2 gap < GAPTHR for exact fixup.
// ----------------------------------------------------------------------------
__global__ __launch_bounds__(256)
void gate_kernel(const uint16_t* __restrict__ hbf, const float* __restrict__ gW,
                 const float* __restrict__ cW, const float* __restrict__ cb,
                 int* __restrict__ eidx, float* __restrict__ s0,
                 float* __restrict__ c1, int* __restrict__ nflag,
                 int* __restrict__ flaglist)
{
  const int lane = threadIdx.x & 63;
  const int row  = blockIdx.x * 4 + (threadIdx.x >> 6);
  const uint16_t* hrow = hbf + (size_t)row * HD;
  float a[10];
#pragma unroll
  for (int i = 0; i < 10; ++i) a[i] = 0.f;
  for (int kk = 0; kk < HD / 64; ++kk) {
    const int k = kk * 64 + lane;
    const float hv = u2f(hrow[k]);
    float4 g0 = *(const float4*)(gW + (size_t)k * 8);
    float4 g1 = *(const float4*)(gW + (size_t)k * 8 + 4);
    a[0] += hv * g0.x; a[1] += hv * g0.y; a[2] += hv * g0.z; a[3] += hv * g0.w;
    a[4] += hv * g1.x; a[5] += hv * g1.y; a[6] += hv * g1.z; a[7] += hv * g1.w;
    float2 cv = *(const float2*)(cW + (size_t)k * 2);
    a[8] += hv * cv.x; a[9] += hv * cv.y;
  }
#pragma unroll
  for (int off = 32; off > 0; off >>= 1) {
#pragma unroll
    for (int i = 0; i < 10; ++i) a[i] += __shfl_xor(a[i], off);
  }
  if (lane == 0) {
    int best = 0; float bm = a[0];
#pragma unroll
    for (int e2 = 1; e2 < 8; ++e2) if (a[e2] > bm) { bm = a[e2]; best = e2; }
    float sec = -3.0e38f;
#pragma unroll
    for (int e2 = 0; e2 < 8; ++e2) if (e2 != best) sec = fmaxf(sec, a[e2]);
    float s = 0.f;
#pragma unroll
    for (int e2 = 0; e2 < 8; ++e2) s += expf(a[e2] - bm);
    const float p  = 1.f / s;
    const float l0 = a[8] + cb[0], l1 = a[9] + cb[1];
    const float mx = fmaxf(l0, l1);
    const float e0 = expf(l0 - mx), e1 = expf(l1 - mx);
    const float inv = 1.f / (e0 + e1);
    eidx[row] = best;
    s0[row]   = p * (e0 * inv);
    c1[row]   = e1 * inv;
    if (bm - sec < GAPTHR) {
      int fi = atomicAdd(nflag, 1);
      if (fi < MAXFLAG) flaglist[fi] = row;
    }
  }
}

// ----------------------------------------------------------------------------
// fixup1: zpart[kb][f][j] = sum_{k in 128-chunk kb} x[row_f][k] * enc_W[k][j]
// grid (16 jb, 16 kb) = 256 blocks, disjoint W slabs (32 regs/thread).
// Row batches of 8: one barrier pair per batch, 8 indep f64 chains/thread,
// all 256 threads store.  Deterministic (fixed split + order, no atomics).
// ----------------------------------------------------------------------------
__global__ __launch_bounds__(256)
void fixup1_kernel(const float* __restrict__ x, const float* __restrict__ encW,
                   const int* __restrict__ flaglist, const int* __restrict__ nflag,
                   float* __restrict__ zpart)   // [16][MAXFLAG][HD]
{
  __shared__ float xs[8][128];
  __shared__ double red[8][4][64];
  int nf = *nflag; if (nf > MAXFLAG) nf = MAXFLAG;
  if (nf <= 0) return;
  const int t  = threadIdx.x;
  const int jb = blockIdx.x, kb = blockIdx.y;
  const int tj = t & 63, tk = t >> 6;          // tk in [0,4)
  const int j  = jb * 64 + tj;
  const int k0 = kb * 128 + tk * 32;
  float w[32];
#pragma unroll
  for (int kk = 0; kk < 32; ++kk)
    w[kk] = encW[(size_t)(k0 + kk) * HD + j];

  const int nb = (nf + 7) >> 3;
  for (int fb = 0; fb < nb; ++fb) {
    __syncthreads();                           // xs/red reuse across batches
    {
      const int r  = t >> 5;                   // 0..7
      const int kc = (t & 31) * 4;
      int f = fb * 8 + r; if (f > nf - 1) f = nf - 1;
      const int row = flaglist[f];
      *(float4*)&xs[r][kc] =
          *(const float4*)&x[(size_t)row * DIN + kb * 128 + kc];
    }
    __syncthreads();
    double acc[8];
#pragma unroll
    for (int r = 0; r < 8; ++r) acc[r] = 0.0;
#pragma unroll
    for (int kk = 0; kk < 32; ++kk) {
      const double wv = (double)w[kk];
#pragma unroll
      for (int r = 0; r < 8; ++r)
        acc[r] += (double)xs[r][tk * 32 + kk] * wv;
    }
#pragma unroll
    for (int r = 0; r < 8; ++r) red[r][tk][tj] = acc[r];
    __syncthreads();
#pragma unroll
    for (int p = 0; p < 2; ++p) {
      const int idx = p * 256 + t;
      const int r = idx >> 6, jj = idx & 63;
      const int f = fb * 8 + r;
      if (f < nf)
        zpart[((size_t)kb * MAXFLAG + f) * HD + jb * 64 + jj] =
            (float)((red[r][0][jj] + red[r][1][jj]) +
                    (red[r][2][jj] + red[r][3][jj]));
    }
  }
}

// ----------------------------------------------------------------------------
// fixup2: exact gate for flagged rows (16 k-partials); overwrites eidx/s0/c1.
// ----------------------------------------------------------------------------
__global__ __launch_bounds__(256)
void fixup2_kernel(const float* __restrict__ zpart, const float* __restrict__ encB,
                   const float* __restrict__ gW, const float* __restrict__ cW,
                   const float* __restrict__ cb, const int* __restrict__ flaglist,
                   const int* __restrict__ nflag, int* __restrict__ eidx,
                   float* __restrict__ s0, float* __restrict__ c1)
{
  __shared__ double red[4][10];
  int nf = *nflag; if (nf > MAXFLAG) nf = MAXFLAG;
  const int t = threadIdx.x, lane = t & 63, w = t >> 6;
  for (int f = blockIdx.x; f < nf; f += 128) {
    const int row = flaglist[f];
    double part[10];
#pragma unroll
    for (int i = 0; i < 10; ++i) part[i] = 0.0;
    for (int jj = t; jj < HD; jj += 256) {
      double z = 0.0;
#pragma unroll
      for (int kb = 0; kb < 16; ++kb)
        z += (double)zpart[((size_t)kb * MAXFLAG + f) * HD + jj];
      double hj = z + (double)encB[jj];
      hj = hj > 0.0 ? hj : 0.0;
      const float* gr = gW + (size_t)jj * 8;
#pragma unroll
      for (int e2 = 0; e2 < 8; ++e2) part[e2] += hj * (double)gr[e2];
      part[8] += hj * (double)cW[jj * 2];
      part[9] += hj * (double)cW[jj * 2 + 1];
    }
#pragma unroll
    for (int off = 32; off > 0; off >>= 1)
#pragma unroll
      for (int i = 0; i < 10; ++i) part[i] += __shfl_xor(part[i], off);
    if (lane == 0)
#pragma unroll
      for (int i = 0; i < 10; ++i) red[w][i] = part[i];
    __syncthreads();
    if (t == 0) {
      double a[10];
#pragma unroll
      for (int i = 0; i < 10; ++i)
        a[i] = red[0][i] + red[1][i] + red[2][i] + red[3][i];
      int best = 0; double bm = a[0];
#pragma unroll
      for (int e2 = 1; e2 < 8; ++e2) if (a[e2] > bm) { bm = a[e2]; best = e2; }
      double s = 0.0;
#pragma unroll
      for (int e2 = 0; e2 < 8; ++e2) s += exp(a[e2] - bm);
      const double p  = 1.0 / s;
      const double l0 = a[8] + (double)cb[0], l1 = a[9] + (double)cb[1];
      const double mx = l0 > l1 ? l0 : l1;
      const double e0 = exp(l0 - mx), e1 = exp(l1 - mx);
      const double inv = 1.0 / (e0 + e1);
      eidx[row] = best;
      s0[row]   = (float)(p * e0 * inv);
      c1[row]   = (float)(e1 * inv);
    }
    __syncthreads();
  }
}

__global__ __launch_bounds__(256)
void count_kernel(const int* __restrict__ eidx, unsigned* __restrict__ cnt) {
  const int n = blockIdx.x * 256 + threadIdx.x;
  atomicAdd(&cnt[eidx[n]], 1u);
}

__global__ void scan_kernel(const unsigned* __restrict__ cnt,
                            int* __restrict__ tinfo, int* __restrict__ offs,
                            int* __restrict__ cursor) {
  if (threadIdx.x == 0 && blockIdx.x == 0) {
    int off = 0, nt = 0;
    for (int e = 0; e < NEXP; ++e) {
      offs[e] = off; cursor[e] = 0;
      const int c = (int)cnt[e];
      const int end = off + c;
      for (int r = 0; r < c; r += 128) {
        tinfo[1 + nt * 3 + 0] = e;
        tinfo[1 + nt * 3 + 1] = off + r;
        tinfo[1 + nt * 3 + 2] = end;
        ++nt;
      }
      off = end;
    }
    tinfo[0] = nt;
  }
}

__global__ __launch_bounds__(256)
void scatter_kernel(const int* __restrict__ eidx, const int* __restrict__ offs,
                    int* __restrict__ cursor, int* __restrict__ rowperm) {
  const int n = blockIdx.x * 256 + threadIdx.x;
  const int e = eidx[n];
  rowperm[offs[e] + atomicAdd(&cursor[e], 1)] = n;
}

// ----------------------------------------------------------------------------
extern "C" void kernel_launch(void* const* d_in, const int* in_sizes, int n_in,
                              void* d_out, int out_size, void* d_ws, size_t ws_size,
                              hipStream_t stream) {
  (void)in_sizes; (void)n_in; (void)out_size;
  const float* x      = (const float*)d_in[0];
  const float* enc_W  = (const float*)d_in[1];
  const float* enc_b  = (const float*)d_in[2];
  const float* gate_W = (const float*)d_in[3];
  const float* exp_W  = (const float*)d_in[4];
  const float* exp_b  = (const float*)d_in[5];
  const float* mlp_W  = (const float*)d_in[6];
  const float* mlp_b  = (const float*)d_in[7];
  const float* coef_W = (const float*)d_in[8];
  const float* coef_b = (const float*)d_in[9];
  const float* dec_W  = (const float*)d_in[10];
  const float* dec_b  = (const float*)d_in[11];

  char* ws = (char*)d_ws;
  size_t off = 0;
  auto alloc = [&](size_t bytes) {
    char* p = ws + off;
    off += (bytes + 255) & ~(size_t)255;
    return p;
  };
  uint16_t* encWT  = (uint16_t*)alloc((size_t)DIN * HD * 2);          //  4 MiB
  uint16_t* mlpWT  = (uint16_t*)alloc((size_t)HD * HD * 2);           //  2 MiB
  uint16_t* decWT  = (uint16_t*)alloc((size_t)HD * DIN * 2);          //  4 MiB
  uint16_t* expWT  = (uint16_t*)alloc((size_t)NEXP * HD * HD * 2);    // 16 MiB
  uint16_t* h_bf   = (uint16_t*)alloc((size_t)NROWS * HD * 2);        // 16 MiB
  float*    zpart  = (float*)   alloc((size_t)16 * MAXFLAG * HD * 4); // 32 MiB
  int*      eidx   = (int*)     alloc(NROWS * 4);
  float*    s0     = (float*)   alloc(NROWS * 4);
  float*    c1     = (float*)   alloc(NROWS * 4);
  int*      rowperm= (int*)     alloc(NROWS * 4);
  int*      flags  = (int*)     alloc(MAXFLAG * 4);
  char*     ctrs   = (char*)    alloc(256);
  int*      offs   = (int*)     alloc(64);
  int*      cursor = (int*)     alloc(64);
  int*      tinfo  = (int*)     alloc((1 + MAX_TILES * 3) * 4 + 64);
  // accout aliases zpart: zpart dead after fixup2; expert GEMM then writes
  // every element of accout before mlp/dec read it.
  uint16_t* accout = (uint16_t*)zpart;
  unsigned* cnt    = (unsigned*)ctrs;
  int*      nflag  = (int*)(ctrs + 32);
  if (off > ws_size) return;

  hipMemsetAsync(ctrs, 0, 256, stream);

  const dim3 blk(256);
  tcast_k<<<dim3(HD / 64, DIN / 64, 1),    blk, 0, stream>>>(enc_W, encWT, DIN, HD);
  tcast_k<<<dim3(HD / 64, HD / 64, 1),     blk, 0, stream>>>(mlp_W, mlpWT, HD, HD);
  tcast_k<<<dim3(DIN / 64, HD / 64, 1),    blk, 0, stream>>>(dec_W, decWT, HD, DIN);
  tcast_k<<<dim3(HD / 64, HD / 64, NEXP),  blk, 0, stream>>>(exp_W, expWT, HD, HD);

  gemm_kernel<0><<<dim3(NROWS / 128, HD / 128), blk, 0, stream>>>(
      x, encWT, h_bf, nullptr, enc_b, nullptr, nullptr, nullptr,
      NROWS, HD, DIN);

  gate_kernel<<<dim3(NROWS / 4), blk, 0, stream>>>(
      h_bf, gate_W, coef_W, coef_b, eidx, s0, c1, nflag, flags);
  fixup1_kernel<<<dim3(16, 16), blk, 0, stream>>>(x, enc_W, flags, nflag, zpart);
  fixup2_kernel<<<dim3(128), blk, 0, stream>>>(
      zpart, enc_b, gate_W, coef_W, coef_b, flags, nflag, eidx, s0, c1);

  count_kernel<<<dim3(NROWS / 256), blk, 0, stream>>>(eidx, cnt);
  scan_kernel<<<1, 64, 0, stream>>>(cnt, tinfo, offs, cursor);
  scatter_kernel<<<dim3(NROWS / 256), blk, 0, stream>>>(eidx, offs, cursor, rowperm);

  gemm_kernel<1><<<dim3(MAX_TILES, HD / 128), blk, 0, stream>>>(
      h_bf, expWT, accout, nullptr, exp_b, rowperm, tinfo, s0,
      NROWS, HD, HD);
  gemm_kernel<2><<<dim3(NROWS / 128, HD / 128), blk, 0, stream>>>(
      h_bf, mlpWT, accout, nullptr, mlp_b, nullptr, nullptr, c1,
      NROWS, HD, HD);
  gemm_kernel<3><<<dim3(NROWS / 128, DIN / 128), blk, 0, stream>>>(
      accout, decWT, nullptr, (float*)d_out, dec_b, nullptr, nullptr, nullptr,
      NROWS, DIN, HD);
}

// Round 6
// 431.082 us; speedup vs baseline: 1.8010x; 1.1294x over previous
//
#include <hip/hip_runtime.h>
#include <hip/hip_bf16.h>
#include <stdint.h>

// ============================================================================
// MoE Autoencoder (N=8192, D_IN=2048, H=1024, E=8).  f32 in / f32 out,
// bf16-tolerance (0.0625) => bf16 MFMA compute.
// Round 6: fixup1 occupancy fix — row-split over blockIdx.z (x4 blocks).
//   R5 showed 1 block/CU (occ 11%) left the f64+LDS chain latency-exposed.
// ============================================================================

using bf16 = __hip_bfloat16;
typedef __bf16 bf16x8 __attribute__((ext_vector_type(8)));
typedef float f32x4 __attribute__((ext_vector_type(4)));

static constexpr int NROWS = 8192;
static constexpr int DIN   = 2048;
static constexpr int HD    = 1024;
static constexpr int NEXP  = 8;
static constexpr int MAX_TILES = 72;     // sum_e ceil(cnt_e/128) <= 64+7
static constexpr int MAXFLAG = 512;      // measured nf ~ 345
#define GAPTHR 0.02f

__device__ __forceinline__ uint16_t f2u(float f) {
  bf16 h = __float2bfloat16(f);
  uint16_t u; __builtin_memcpy(&u, &h, 2); return u;
}
__device__ __forceinline__ float u2f(uint16_t u) {
  uint32_t x = ((uint32_t)u) << 16;
  float f; __builtin_memcpy(&f, &x, 4); return f;
}

typedef const __attribute__((address_space(1))) void* gas_ptr;
typedef __attribute__((address_space(3))) void* las_ptr;
__device__ __forceinline__ void async16(void* lds, const void* g) {
  __builtin_amdgcn_global_load_lds((gas_ptr)g, (las_ptr)lds, 16, 0, 0);
}

// ----------------------------------------------------------------------------
// 64x64-tile transpose + cast f32 -> bf16: out[C][R] = bf16(in[R][C]).
// ----------------------------------------------------------------------------
__global__ __launch_bounds__(256)
void tcast_k(const float* __restrict__ in, uint16_t* __restrict__ out,
             int R, int C) {
  __shared__ float tile[64 * 65];
  const int t  = threadIdx.x;
  const int C0 = blockIdx.x * 64, R0 = blockIdx.y * 64;
  in  += (size_t)blockIdx.z * R * C;
  out += (size_t)blockIdx.z * R * C;
  const int cl = (t & 7) * 8;
#pragma unroll
  for (int p = 0; p < 2; ++p) {
    const int r = p * 32 + (t >> 3);
    const float* src = in + (size_t)(R0 + r) * C + C0 + cl;
    float4 v0 = *(const float4*)(src);
    float4 v1 = *(const float4*)(src + 4);
    float* dst = &tile[r * 65 + cl];
    dst[0] = v0.x; dst[1] = v0.y; dst[2] = v0.z; dst[3] = v0.w;
    dst[4] = v1.x; dst[5] = v1.y; dst[6] = v1.z; dst[7] = v1.w;
  }
  __syncthreads();
#pragma unroll
  for (int p = 0; p < 2; ++p) {
    const int oc = p * 32 + (t >> 3);
    uint16_t tmp[8];
#pragma unroll
    for (int j = 0; j < 8; ++j) tmp[j] = f2u(tile[(cl + j) * 65 + oc]);
    int4 v; __builtin_memcpy(&v, tmp, 16);
    *(int4*)(out + (size_t)(C0 + oc) * R + R0 + cl) = v;
  }
}

// ----------------------------------------------------------------------------
// 128x128-tile GEMM, BK=64, 4 waves:  C = epilogue(A[M,K] @ BT[N,K]^T)
// MODE 0: enc  — A is f32 (reg-stage cast); relu(acc+b) -> C16 (bf16)
// MODE 1: exp  — gathered rows; (acc + b_e) * scale[orig], scattered (bf16)
// MODE 2: mlp  — C16[r,c] += (acc + b) * scale[r]         (bf16 RMW)
// MODE 3: dec  — C32 = acc + b                            (f32 out)
// ----------------------------------------------------------------------------
template<int MODE>
__global__ __launch_bounds__(256)
void gemm_kernel(const void* __restrict__ Av, const uint16_t* __restrict__ BT,
                 uint16_t* __restrict__ C16, float* __restrict__ C32,
                 const float* __restrict__ biasf,
                 const int* __restrict__ rowperm, const int* __restrict__ tinfo,
                 const float* __restrict__ scale, int M, int N, int K)
{
  const int t = threadIdx.x;
  const int mtile = blockIdx.x, ntile = blockIdx.y;

  int e = 0, row0 = 0, rowend = 0;
  if constexpr (MODE == 1) {
    const int nt = tinfo[0];
    if (mtile >= nt) return;
    e      = tinfo[1 + mtile * 3 + 0];
    row0   = tinfo[1 + mtile * 3 + 1];
    rowend = tinfo[1 + mtile * 3 + 2];
  }

  __shared__ uint16_t As[128 * 64];
  __shared__ uint16_t Bs[128 * 64];

  const int kcol = (t & 7) * 8;
  const char* asrc[4];
  const uint16_t* bsrc[4];
  const int aelt = (MODE == 0) ? 4 : 2;
#pragma unroll
  for (int c = 0; c < 4; ++c) {
    const int r = c * 32 + (t >> 3);
    int arow;
    if constexpr (MODE == 1) {
      int pr = row0 + r;
      if (pr > rowend - 1) pr = rowend - 1;     // pad rows clamped, masked later
      arow = rowperm[pr];
    } else {
      arow = mtile * 128 + r;
    }
    asrc[c] = (const char*)Av + ((size_t)arow * K + kcol) * aelt;
    size_t brow = (size_t)ntile * 128 + r;
    if constexpr (MODE == 1) brow += (size_t)e * N;   // expWT: [E][N][K]
    bsrc[c] = BT + brow * (size_t)K + kcol;
  }

  f32x4 acc[4][4];
  const f32x4 zero = {0.f, 0.f, 0.f, 0.f};
#pragma unroll
  for (int i = 0; i < 4; ++i)
#pragma unroll
    for (int j = 0; j < 4; ++j) acc[i][j] = zero;

  const int wid = t >> 6, lane = t & 63;
  const int wm = wid >> 1, wn = wid & 1;
  const int frow = lane & 15;
  const int fk = (lane >> 4) * 8;

  const int nk = K >> 6;
  for (int kt = 0; kt < nk; ++kt) {
    if constexpr (MODE == 0) {
#pragma unroll
      for (int c = 0; c < 4; ++c) {
        const float* s = (const float*)asrc[c] + kt * 64;
        float4 v0 = *(const float4*)(s);
        float4 v1 = *(const float4*)(s + 4);
        uint16_t tmp[8];
        tmp[0] = f2u(v0.x); tmp[1] = f2u(v0.y); tmp[2] = f2u(v0.z); tmp[3] = f2u(v0.w);
        tmp[4] = f2u(v1.x); tmp[5] = f2u(v1.y); tmp[6] = f2u(v1.z); tmp[7] = f2u(v1.w);
        int4 pv; __builtin_memcpy(&pv, tmp, 16);
        *(int4*)&As[c * 2048 + t * 8] = pv;
      }
#pragma unroll
      for (int c = 0; c < 4; ++c)
        async16(&Bs[c * 2048 + t * 8], bsrc[c] + kt * 64);
    } else {
#pragma unroll
      for (int c = 0; c < 4; ++c) {
        async16(&As[c * 2048 + t * 8], (const uint16_t*)asrc[c] + kt * 64);
        async16(&Bs[c * 2048 + t * 8], bsrc[c] + kt * 64);
      }
    }
    __syncthreads();
#pragma unroll
    for (int kk = 0; kk < 2; ++kk) {
      bf16x8 af[4], bfr[4];
#pragma unroll
      for (int mi = 0; mi < 4; ++mi)
        af[mi] = *reinterpret_cast<const bf16x8*>(
            &As[(wm * 64 + mi * 16 + frow) * 64 + kk * 32 + fk]);
#pragma unroll
      for (int ni = 0; ni < 4; ++ni)
        bfr[ni] = *reinterpret_cast<const bf16x8*>(
            &Bs[(wn * 64 + ni * 16 + frow) * 64 + kk * 32 + fk]);
#pragma unroll
      for (int mi = 0; mi < 4; ++mi)
#pragma unroll
        for (int ni = 0; ni < 4; ++ni)
          acc[mi][ni] = __builtin_amdgcn_mfma_f32_16x16x32_bf16(
              af[mi], bfr[ni], acc[mi][ni], 0, 0, 0);
    }
    __syncthreads();
  }

  // epilogue — C/D layout: col = lane&15, row = (lane>>4)*4 + j   [m89]
  const int nbase = ntile * 128 + wn * 64;
  const int rbase = wm * 64 + (lane >> 4) * 4;
  const int cbase = lane & 15;
#pragma unroll
  for (int mi = 0; mi < 4; ++mi) {
#pragma unroll
    for (int j = 0; j < 4; ++j) {
      const int rr = rbase + mi * 16 + j;
      if constexpr (MODE == 1) {
        const int pr = row0 + rr;
        if (pr < rowend) {
          const int orig = rowperm[pr];
          const float sc = scale[orig];
          uint16_t* dst = C16 + (size_t)orig * N;
#pragma unroll
          for (int ni = 0; ni < 4; ++ni) {
            const int gc = nbase + ni * 16 + cbase;
            dst[gc] = f2u((acc[mi][ni][j] + biasf[e * N + gc]) * sc);
          }
        }
      } else {
        const int gr = mtile * 128 + rr;
#pragma unroll
        for (int ni = 0; ni < 4; ++ni) {
          const int gc = nbase + ni * 16 + cbase;
          float v = acc[mi][ni][j] + biasf[gc];
          if constexpr (MODE == 0) {
            C16[(size_t)gr * N + gc] = f2u(fmaxf(v, 0.f));
          } else if constexpr (MODE == 2) {
            const float prev = u2f(C16[(size_t)gr * N + gc]);
            C16[(size_t)gr * N + gc] = f2u(prev + v * scale[gr]);
          } else {
            C32[(size_t)gr * N + gc] = v;
          }
        }
      }
    }
  }
}

// ----------------------------------------------------------------------------
// Gate from bf16 h: logits = h @ gate_W, coef = softmax(h @ coef_W + cb).
// One wave per row; flags rows with top2 gap < GAPTHR for exact fixup.
// ----------------------------------------------------------------------------
__global__ __launch_bounds__(256)
void gate_kernel(const uint16_t* __restrict__ hbf, const float* __restrict__ gW,
                 const float* __restrict__ cW, const float* __restrict__ cb,
                 int* __restrict__ eidx, float* __restrict__ s0,
                 float* __restrict__ c1, int* __restrict__ nflag,
                 int* __restrict__ flaglist)
{
  const int lane = threadIdx.x & 63;
  const int row  = blockIdx.x * 4 + (threadIdx.x >> 6);
  const uint16_t* hrow = hbf + (size_t)row * HD;
  float a[10];
#pragma unroll
  for (int i = 0; i < 10; ++i) a[i] = 0.f;
  for (int kk = 0; kk < HD / 64; ++kk) {
    const int k = kk * 64 + lane;
    const float hv = u2f(hrow[k]);
    float4 g0 = *(const float4*)(gW + (size_t)k * 8);
    float4 g1 = *(const float4*)(gW + (size_t)k * 8 + 4);
    a[0] += hv * g0.x; a[1] += hv * g0.y; a[2] += hv * g0.z; a[3] += hv * g0.w;
    a[4] += hv * g1.x; a[5] += hv * g1.y; a[6] += hv * g1.z; a[7] += hv * g1.w;
    float2 cv = *(const float2*)(cW + (size_t)k * 2);
    a[8] += hv * cv.x; a[9] += hv * cv.y;
  }
#pragma unroll
  for (int off = 32; off > 0; off >>= 1) {
#pragma unroll
    for (int i = 0; i < 10; ++i) a[i] += __shfl_xor(a[i], off);
  }
  if (lane == 0) {
    int best = 0; float bm = a[0];
#pragma unroll
    for (int e2 = 1; e2 < 8; ++e2) if (a[e2] > bm) { bm = a[e2]; best = e2; }
    float sec = -3.0e38f;
#pragma unroll
    for (int e2 = 0; e2 < 8; ++e2) if (e2 != best) sec = fmaxf(sec, a[e2]);
    float s = 0.f;
#pragma unroll
    for (int e2 = 0; e2 < 8; ++e2) s += expf(a[e2] - bm);
    const float p  = 1.f / s;
    const float l0 = a[8] + cb[0], l1 = a[9] + cb[1];
    const float mx = fmaxf(l0, l1);
    const float e0 = expf(l0 - mx), e1 = expf(l1 - mx);
    const float inv = 1.f / (e0 + e1);
    eidx[row] = best;
    s0[row]   = p * (e0 * inv);
    c1[row]   = e1 * inv;
    if (bm - sec < GAPTHR) {
      int fi = atomicAdd(nflag, 1);
      if (fi < MAXFLAG) flaglist[fi] = row;
    }
  }
}

// ----------------------------------------------------------------------------
// fixup1: zpart[kb][f][j] = sum_{k in 128-chunk kb} x[row_f][k] * enc_W[k][j]
// grid (16 jb, 16 kb, 4 rs) = 1024 blocks (4/CU).  Disjoint W slabs per
// (jb,kb); row-batches striped over rs.  Deterministic (no atomics).
// ----------------------------------------------------------------------------
__global__ __launch_bounds__(256)
void fixup1_kernel(const float* __restrict__ x, const float* __restrict__ encW,
                   const int* __restrict__ flaglist, const int* __restrict__ nflag,
                   float* __restrict__ zpart)   // [16][MAXFLAG][HD]
{
  __shared__ float xs[8][128];
  __shared__ double red[8][4][64];
  int nf = *nflag; if (nf > MAXFLAG) nf = MAXFLAG;
  if (nf <= 0) return;
  const int t  = threadIdx.x;
  const int jb = blockIdx.x, kb = blockIdx.y, rs = blockIdx.z;
  const int tj = t & 63, tk = t >> 6;          // tk in [0,4)
  const int j  = jb * 64 + tj;
  const int k0 = kb * 128 + tk * 32;
  float w[32];
#pragma unroll
  for (int kk = 0; kk < 32; ++kk)
    w[kk] = encW[(size_t)(k0 + kk) * HD + j];

  const int nb = (nf + 7) >> 3;
  for (int fb = rs; fb < nb; fb += 4) {
    __syncthreads();                           // xs/red reuse across batches
    {
      const int r  = t >> 5;                   // 0..7
      const int kc = (t & 31) * 4;
      int f = fb * 8 + r; if (f > nf - 1) f = nf - 1;
      const int row = flaglist[f];
      *(float4*)&xs[r][kc] =
          *(const float4*)&x[(size_t)row * DIN + kb * 128 + kc];
    }
    __syncthreads();
    double acc[8];
#pragma unroll
    for (int r = 0; r < 8; ++r) acc[r] = 0.0;
#pragma unroll
    for (int kk = 0; kk < 32; ++kk) {
      const double wv = (double)w[kk];
#pragma unroll
      for (int r = 0; r < 8; ++r)
        acc[r] += (double)xs[r][tk * 32 + kk] * wv;
    }
#pragma unroll
    for (int r = 0; r < 8; ++r) red[r][tk][tj] = acc[r];
    __syncthreads();
#pragma unroll
    for (int p = 0; p < 2; ++p) {
      const int idx = p * 256 + t;
      const int r = idx >> 6, jj = idx & 63;
      const int f = fb * 8 + r;
      if (f < nf)
        zpart[((size_t)kb * MAXFLAG + f) * HD + jb * 64 + jj] =
            (float)((red[r][0][jj] + red[r][1][jj]) +
                    (red[r][2][jj] + red[r][3][jj]));
    }
  }
}

// ----------------------------------------------------------------------------
// fixup2: exact gate for flagged rows (16 k-partials); overwrites eidx/s0/c1.
// ----------------------------------------------------------------------------
__global__ __launch_bounds__(256)
void fixup2_kernel(const float* __restrict__ zpart, const float* __restrict__ encB,
                   const float* __restrict__ gW, const float* __restrict__ cW,
                   const float* __restrict__ cb, const int* __restrict__ flaglist,
                   const int* __restrict__ nflag, int* __restrict__ eidx,
                   float* __restrict__ s0, float* __restrict__ c1)
{
  __shared__ double red[4][10];
  int nf = *nflag; if (nf > MAXFLAG) nf = MAXFLAG;
  const int t = threadIdx.x, lane = t & 63, w = t >> 6;
  for (int f = blockIdx.x; f < nf; f += 128) {
    const int row = flaglist[f];
    double part[10];
#pragma unroll
    for (int i = 0; i < 10; ++i) part[i] = 0.0;
    for (int jj = t; jj < HD; jj += 256) {
      double z = 0.0;
#pragma unroll
      for (int kb = 0; kb < 16; ++kb)
        z += (double)zpart[((size_t)kb * MAXFLAG + f) * HD + jj];
      double hj = z + (double)encB[jj];
      hj = hj > 0.0 ? hj : 0.0;
      const float* gr = gW + (size_t)jj * 8;
#pragma unroll
      for (int e2 = 0; e2 < 8; ++e2) part[e2] += hj * (double)gr[e2];
      part[8] += hj * (double)cW[jj * 2];
      part[9] += hj * (double)cW[jj * 2 + 1];
    }
#pragma unroll
    for (int off = 32; off > 0; off >>= 1)
#pragma unroll
      for (int i = 0; i < 10; ++i) part[i] += __shfl_xor(part[i], off);
    if (lane == 0)
#pragma unroll
      for (int i = 0; i < 10; ++i) red[w][i] = part[i];
    __syncthreads();
    if (t == 0) {
      double a[10];
#pragma unroll
      for (int i = 0; i < 10; ++i)
        a[i] = red[0][i] + red[1][i] + red[2][i] + red[3][i];
      int best = 0; double bm = a[0];
#pragma unroll
      for (int e2 = 1; e2 < 8; ++e2) if (a[e2] > bm) { bm = a[e2]; best = e2; }
      double s = 0.0;
#pragma unroll
      for (int e2 = 0; e2 < 8; ++e2) s += exp(a[e2] - bm);
      const double p  = 1.0 / s;
      const double l0 = a[8] + (double)cb[0], l1 = a[9] + (double)cb[1];
      const double mx = l0 > l1 ? l0 : l1;
      const double e0 = exp(l0 - mx), e1 = exp(l1 - mx);
      const double inv = 1.0 / (e0 + e1);
      eidx[row] = best;
      s0[row]   = (float)(p * e0 * inv);
      c1[row]   = (float)(e1 * inv);
    }
    __syncthreads();
  }
}

__global__ __launch_bounds__(256)
void count_kernel(const int* __restrict__ eidx, unsigned* __restrict__ cnt) {
  const int n = blockIdx.x * 256 + threadIdx.x;
  atomicAdd(&cnt[eidx[n]], 1u);
}

__global__ void scan_kernel(const unsigned* __restrict__ cnt,
                            int* __restrict__ tinfo, int* __restrict__ offs,
                            int* __restrict__ cursor) {
  if (threadIdx.x == 0 && blockIdx.x == 0) {
    int off = 0, nt = 0;
    for (int e = 0; e < NEXP; ++e) {
      offs[e] = off; cursor[e] = 0;
      const int c = (int)cnt[e];
      const int end = off + c;
      for (int r = 0; r < c; r += 128) {
        tinfo[1 + nt * 3 + 0] = e;
        tinfo[1 + nt * 3 + 1] = off + r;
        tinfo[1 + nt * 3 + 2] = end;
        ++nt;
      }
      off = end;
    }
    tinfo[0] = nt;
  }
}

__global__ __launch_bounds__(256)
void scatter_kernel(const int* __restrict__ eidx, const int* __restrict__ offs,
                    int* __restrict__ cursor, int* __restrict__ rowperm) {
  const int n = blockIdx.x * 256 + threadIdx.x;
  const int e = eidx[n];
  rowperm[offs[e] + atomicAdd(&cursor[e], 1)] = n;
}

// ----------------------------------------------------------------------------
extern "C" void kernel_launch(void* const* d_in, const int* in_sizes, int n_in,
                              void* d_out, int out_size, void* d_ws, size_t ws_size,
                              hipStream_t stream) {
  (void)in_sizes; (void)n_in; (void)out_size;
  const float* x      = (const float*)d_in[0];
  const float* enc_W  = (const float*)d_in[1];
  const float* enc_b  = (const float*)d_in[2];
  const float* gate_W = (const float*)d_in[3];
  const float* exp_W  = (const float*)d_in[4];
  const float* exp_b  = (const float*)d_in[5];
  const float* mlp_W  = (const float*)d_in[6];
  const float* mlp_b  = (const float*)d_in[7];
  const float* coef_W = (const float*)d_in[8];
  const float* coef_b = (const float*)d_in[9];
  const float* dec_W  = (const float*)d_in[10];
  const float* dec_b  = (const float*)d_in[11];

  char* ws = (char*)d_ws;
  size_t off = 0;
  auto alloc = [&](size_t bytes) {
    char* p = ws + off;
    off += (bytes + 255) & ~(size_t)255;
    return p;
  };
  uint16_t* encWT  = (uint16_t*)alloc((size_t)DIN * HD * 2);          //  4 MiB
  uint16_t* mlpWT  = (uint16_t*)alloc((size_t)HD * HD * 2);           //  2 MiB
  uint16_t* decWT  = (uint16_t*)alloc((size_t)HD * DIN * 2);          //  4 MiB
  uint16_t* expWT  = (uint16_t*)alloc((size_t)NEXP * HD * HD * 2);    // 16 MiB
  uint16_t* h_bf   = (uint16_t*)alloc((size_t)NROWS * HD * 2);        // 16 MiB
  float*    zpart  = (float*)   alloc((size_t)16 * MAXFLAG * HD * 4); // 32 MiB
  int*      eidx   = (int*)     alloc(NROWS * 4);
  float*    s0     = (float*)   alloc(NROWS * 4);
  float*    c1     = (float*)   alloc(NROWS * 4);
  int*      rowperm= (int*)     alloc(NROWS * 4);
  int*      flags  = (int*)     alloc(MAXFLAG * 4);
  char*     ctrs   = (char*)    alloc(256);
  int*      offs   = (int*)     alloc(64);
  int*      cursor = (int*)     alloc(64);
  int*      tinfo  = (int*)     alloc((1 + MAX_TILES * 3) * 4 + 64);
  // accout aliases zpart: zpart dead after fixup2; expert GEMM then writes
  // every element of accout before mlp/dec read it.
  uint16_t* accout = (uint16_t*)zpart;
  unsigned* cnt    = (unsigned*)ctrs;
  int*      nflag  = (int*)(ctrs + 32);
  if (off > ws_size) return;

  hipMemsetAsync(ctrs, 0, 256, stream);

  const dim3 blk(256);
  tcast_k<<<dim3(HD / 64, DIN / 64, 1),    blk, 0, stream>>>(enc_W, encWT, DIN, HD);
  tcast_k<<<dim3(HD / 64, HD / 64, 1),     blk, 0, stream>>>(mlp_W, mlpWT, HD, HD);
  tcast_k<<<dim3(DIN / 64, HD / 64, 1),    blk, 0, stream>>>(dec_W, decWT, HD, DIN);
  tcast_k<<<dim3(HD / 64, HD / 64, NEXP),  blk, 0, stream>>>(exp_W, expWT, HD, HD);

  gemm_kernel<0><<<dim3(NROWS / 128, HD / 128), blk, 0, stream>>>(
      x, encWT, h_bf, nullptr, enc_b, nullptr, nullptr, nullptr,
      NROWS, HD, DIN);

  gate_kernel<<<dim3(NROWS / 4), blk, 0, stream>>>(
      h_bf, gate_W, coef_W, coef_b, eidx, s0, c1, nflag, flags);
  fixup1_kernel<<<dim3(16, 16, 4), blk, 0, stream>>>(x, enc_W, flags, nflag, zpart);
  fixup2_kernel<<<dim3(128), blk, 0, stream>>>(
      zpart, enc_b, gate_W, coef_W, coef_b, flags, nflag, eidx, s0, c1);

  count_kernel<<<dim3(NROWS / 256), blk, 0, stream>>>(eidx, cnt);
  scan_kernel<<<1, 64, 0, stream>>>(cnt, tinfo, offs, cursor);
  scatter_kernel<<<dim3(NROWS / 256), blk, 0, stream>>>(eidx, offs, cursor, rowperm);

  gemm_kernel<1><<<dim3(MAX_TILES, HD / 128), blk, 0, stream>>>(
      h_bf, expWT, accout, nullptr, exp_b, rowperm, tinfo, s0,
      NROWS, HD, HD);
  gemm_kernel<2><<<dim3(NROWS / 128, HD / 128), blk, 0, stream>>>(
      h_bf, mlpWT, accout, nullptr, mlp_b, nullptr, nullptr, c1,
      NROWS, HD, HD);
  gemm_kernel<3><<<dim3(NROWS / 128, DIN / 128), blk, 0, stream>>>(
      accout, decWT, nullptr, (float*)d_out, dec_b, nullptr, nullptr, nullptr,
      NROWS, DIN, HD);
}

// Round 7
// 429.887 us; speedup vs baseline: 1.8060x; 1.0028x over previous
//
#include <hip/hip_runtime.h>
#include <hip/hip_bf16.h>
#include <stdint.h>

// ============================================================================
// MoE Autoencoder (N=8192, D_IN=2048, H=1024, E=8).  f32 in / f32 out,
// bf16-tolerance (0.0625) => bf16 MFMA compute.
// Round 7:
//   - fixup1: float4 LDS reads (64 b128 vs 256 b32), rs 4->7 (7 blocks/CU)
//   - T1 XCD-aware block swizzle on all GEMMs (grids all %8==0 -> bijective)
// ============================================================================

using bf16 = __hip_bfloat16;
typedef __bf16 bf16x8 __attribute__((ext_vector_type(8)));
typedef float f32x4 __attribute__((ext_vector_type(4)));

static constexpr int NROWS = 8192;
static constexpr int DIN   = 2048;
static constexpr int HD    = 1024;
static constexpr int NEXP  = 8;
static constexpr int MAX_TILES = 72;     // sum_e ceil(cnt_e/128) <= 64+7
static constexpr int MAXFLAG = 512;      // measured nf ~ 345
static constexpr int F1Z = 7;            // fixup1 row-split (blocks/CU)
#define GAPTHR 0.02f

__device__ __forceinline__ uint16_t f2u(float f) {
  bf16 h = __float2bfloat16(f);
  uint16_t u; __builtin_memcpy(&u, &h, 2); return u;
}
__device__ __forceinline__ float u2f(uint16_t u) {
  uint32_t x = ((uint32_t)u) << 16;
  float f; __builtin_memcpy(&f, &x, 4); return f;
}

typedef const __attribute__((address_space(1))) void* gas_ptr;
typedef __attribute__((address_space(3))) void* las_ptr;
__device__ __forceinline__ void async16(void* lds, const void* g) {
  __builtin_amdgcn_global_load_lds((gas_ptr)g, (las_ptr)lds, 16, 0, 0);
}

// ----------------------------------------------------------------------------
// 64x64-tile transpose + cast f32 -> bf16: out[C][R] = bf16(in[R][C]).
// ----------------------------------------------------------------------------
__global__ __launch_bounds__(256)
void tcast_k(const float* __restrict__ in, uint16_t* __restrict__ out,
             int R, int C) {
  __shared__ float tile[64 * 65];
  const int t  = threadIdx.x;
  const int C0 = blockIdx.x * 64, R0 = blockIdx.y * 64;
  in  += (size_t)blockIdx.z * R * C;
  out += (size_t)blockIdx.z * R * C;
  const int cl = (t & 7) * 8;
#pragma unroll
  for (int p = 0; p < 2; ++p) {
    const int r = p * 32 + (t >> 3);
    const float* src = in + (size_t)(R0 + r) * C + C0 + cl;
    float4 v0 = *(const float4*)(src);
    float4 v1 = *(const float4*)(src + 4);
    float* dst = &tile[r * 65 + cl];
    dst[0] = v0.x; dst[1] = v0.y; dst[2] = v0.z; dst[3] = v0.w;
    dst[4] = v1.x; dst[5] = v1.y; dst[6] = v1.z; dst[7] = v1.w;
  }
  __syncthreads();
#pragma unroll
  for (int p = 0; p < 2; ++p) {
    const int oc = p * 32 + (t >> 3);
    uint16_t tmp[8];
#pragma unroll
    for (int j = 0; j < 8; ++j) tmp[j] = f2u(tile[(cl + j) * 65 + oc]);
    int4 v; __builtin_memcpy(&v, tmp, 16);
    *(int4*)(out + (size_t)(C0 + oc) * R + R0 + cl) = v;
  }
}

// ----------------------------------------------------------------------------
// 128x128-tile GEMM, BK=64, 4 waves:  C = epilogue(A[M,K] @ BT[N,K]^T)
// XCD-aware block swizzle (T1): consecutive mtiles (sharing a B panel) land
// on the same XCD's L2.  All grids have nwg % 8 == 0 -> bijective.
// MODE 0: enc  — A is f32 (reg-stage cast); relu(acc+b) -> C16 (bf16)
// MODE 1: exp  — gathered rows; (acc + b_e) * scale[orig], scattered (bf16)
// MODE 2: mlp  — C16[r,c] += (acc + b) * scale[r]         (bf16 RMW)
// MODE 3: dec  — C32 = acc + b                            (f32 out)
// ----------------------------------------------------------------------------
template<int MODE>
__global__ __launch_bounds__(256)
void gemm_kernel(const void* __restrict__ Av, const uint16_t* __restrict__ BT,
                 uint16_t* __restrict__ C16, float* __restrict__ C32,
                 const float* __restrict__ biasf,
                 const int* __restrict__ rowperm, const int* __restrict__ tinfo,
                 const float* __restrict__ scale, int M, int N, int K)
{
  const int t = threadIdx.x;
  // T1 swizzle: flat (x fastest) -> 8-way contiguous chunks per XCD
  const int nwg = gridDim.x * gridDim.y;
  int flat = blockIdx.y * gridDim.x + blockIdx.x;
  flat = (flat & 7) * (nwg >> 3) + (flat >> 3);
  const int mtile = flat % gridDim.x;
  const int ntile = flat / gridDim.x;

  int e = 0, row0 = 0, rowend = 0;
  if constexpr (MODE == 1) {
    const int nt = tinfo[0];
    if (mtile >= nt) return;
    e      = tinfo[1 + mtile * 3 + 0];
    row0   = tinfo[1 + mtile * 3 + 1];
    rowend = tinfo[1 + mtile * 3 + 2];
  }

  __shared__ uint16_t As[128 * 64];
  __shared__ uint16_t Bs[128 * 64];

  const int kcol = (t & 7) * 8;
  const char* asrc[4];
  const uint16_t* bsrc[4];
  const int aelt = (MODE == 0) ? 4 : 2;
#pragma unroll
  for (int c = 0; c < 4; ++c) {
    const int r = c * 32 + (t >> 3);
    int arow;
    if constexpr (MODE == 1) {
      int pr = row0 + r;
      if (pr > rowend - 1) pr = rowend - 1;     // pad rows clamped, masked later
      arow = rowperm[pr];
    } else {
      arow = mtile * 128 + r;
    }
    asrc[c] = (const char*)Av + ((size_t)arow * K + kcol) * aelt;
    size_t brow = (size_t)ntile * 128 + r;
    if constexpr (MODE == 1) brow += (size_t)e * N;   // expWT: [E][N][K]
    bsrc[c] = BT + brow * (size_t)K + kcol;
  }

  f32x4 acc[4][4];
  const f32x4 zero = {0.f, 0.f, 0.f, 0.f};
#pragma unroll
  for (int i = 0; i < 4; ++i)
#pragma unroll
    for (int j = 0; j < 4; ++j) acc[i][j] = zero;

  const int wid = t >> 6, lane = t & 63;
  const int wm = wid >> 1, wn = wid & 1;
  const int frow = lane & 15;
  const int fk = (lane >> 4) * 8;

  const int nk = K >> 6;
  for (int kt = 0; kt < nk; ++kt) {
    if constexpr (MODE == 0) {
#pragma unroll
      for (int c = 0; c < 4; ++c) {
        const float* s = (const float*)asrc[c] + kt * 64;
        float4 v0 = *(const float4*)(s);
        float4 v1 = *(const float4*)(s + 4);
        uint16_t tmp[8];
        tmp[0] = f2u(v0.x); tmp[1] = f2u(v0.y); tmp[2] = f2u(v0.z); tmp[3] = f2u(v0.w);
        tmp[4] = f2u(v1.x); tmp[5] = f2u(v1.y); tmp[6] = f2u(v1.z); tmp[7] = f2u(v1.w);
        int4 pv; __builtin_memcpy(&pv, tmp, 16);
        *(int4*)&As[c * 2048 + t * 8] = pv;
      }
#pragma unroll
      for (int c = 0; c < 4; ++c)
        async16(&Bs[c * 2048 + t * 8], bsrc[c] + kt * 64);
    } else {
#pragma unroll
      for (int c = 0; c < 4; ++c) {
        async16(&As[c * 2048 + t * 8], (const uint16_t*)asrc[c] + kt * 64);
        async16(&Bs[c * 2048 + t * 8], bsrc[c] + kt * 64);
      }
    }
    __syncthreads();
#pragma unroll
    for (int kk = 0; kk < 2; ++kk) {
      bf16x8 af[4], bfr[4];
#pragma unroll
      for (int mi = 0; mi < 4; ++mi)
        af[mi] = *reinterpret_cast<const bf16x8*>(
            &As[(wm * 64 + mi * 16 + frow) * 64 + kk * 32 + fk]);
#pragma unroll
      for (int ni = 0; ni < 4; ++ni)
        bfr[ni] = *reinterpret_cast<const bf16x8*>(
            &Bs[(wn * 64 + ni * 16 + frow) * 64 + kk * 32 + fk]);
#pragma unroll
      for (int mi = 0; mi < 4; ++mi)
#pragma unroll
        for (int ni = 0; ni < 4; ++ni)
          acc[mi][ni] = __builtin_amdgcn_mfma_f32_16x16x32_bf16(
              af[mi], bfr[ni], acc[mi][ni], 0, 0, 0);
    }
    __syncthreads();
  }

  // epilogue — C/D layout: col = lane&15, row = (lane>>4)*4 + j   [m89]
  const int nbase = ntile * 128 + wn * 64;
  const int rbase = wm * 64 + (lane >> 4) * 4;
  const int cbase = lane & 15;
#pragma unroll
  for (int mi = 0; mi < 4; ++mi) {
#pragma unroll
    for (int j = 0; j < 4; ++j) {
      const int rr = rbase + mi * 16 + j;
      if constexpr (MODE == 1) {
        const int pr = row0 + rr;
        if (pr < rowend) {
          const int orig = rowperm[pr];
          const float sc = scale[orig];
          uint16_t* dst = C16 + (size_t)orig * N;
#pragma unroll
          for (int ni = 0; ni < 4; ++ni) {
            const int gc = nbase + ni * 16 + cbase;
            dst[gc] = f2u((acc[mi][ni][j] + biasf[e * N + gc]) * sc);
          }
        }
      } else {
        const int gr = mtile * 128 + rr;
#pragma unroll
        for (int ni = 0; ni < 4; ++ni) {
          const int gc = nbase + ni * 16 + cbase;
          float v = acc[mi][ni][j] + biasf[gc];
          if constexpr (MODE == 0) {
            C16[(size_t)gr * N + gc] = f2u(fmaxf(v, 0.f));
          } else if constexpr (MODE == 2) {
            const float prev = u2f(C16[(size_t)gr * N + gc]);
            C16[(size_t)gr * N + gc] = f2u(prev + v * scale[gr]);
          } else {
            C32[(size_t)gr * N + gc] = v;
          }
        }
      }
    }
  }
}

// ----------------------------------------------------------------------------
// Gate from bf16 h: logits = h @ gate_W, coef = softmax(h @ coef_W + cb).
// One wave per row; flags rows with top2 gap < GAPTHR for exact fixup.
// ----------------------------------------------------------------------------
__global__ __launch_bounds__(256)
void gate_kernel(const uint16_t* __restrict__ hbf, const float* __restrict__ gW,
                 const float* __restrict__ cW, const float* __restrict__ cb,
                 int* __restrict__ eidx, float* __restrict__ s0,
                 float* __restrict__ c1, int* __restrict__ nflag,
                 int* __restrict__ flaglist)
{
  const int lane = threadIdx.x & 63;
  const int row  = blockIdx.x * 4 + (threadIdx.x >> 6);
  const uint16_t* hrow = hbf + (size_t)row * HD;
  float a[10];
#pragma unroll
  for (int i = 0; i < 10; ++i) a[i] = 0.f;
  for (int kk = 0; kk < HD / 64; ++kk) {
    const int k = kk * 64 + lane;
    const float hv = u2f(hrow[k]);
    float4 g0 = *(const float4*)(gW + (size_t)k * 8);
    float4 g1 = *(const float4*)(gW + (size_t)k * 8 + 4);
    a[0] += hv * g0.x; a[1] += hv * g0.y; a[2] += hv * g0.z; a[3] += hv * g0.w;
    a[4] += hv * g1.x; a[5] += hv * g1.y; a[6] += hv * g1.z; a[7] += hv * g1.w;
    float2 cv = *(const float2*)(cW + (size_t)k * 2);
    a[8] += hv * cv.x; a[9] += hv * cv.y;
  }
#pragma unroll
  for (int off = 32; off > 0; off >>= 1) {
#pragma unroll
    for (int i = 0; i < 10; ++i) a[i] += __shfl_xor(a[i], off);
  }
  if (lane == 0) {
    int best = 0; float bm = a[0];
#pragma unroll
    for (int e2 = 1; e2 < 8; ++e2) if (a[e2] > bm) { bm = a[e2]; best = e2; }
    float sec = -3.0e38f;
#pragma unroll
    for (int e2 = 0; e2 < 8; ++e2) if (e2 != best) sec = fmaxf(sec, a[e2]);
    float s = 0.f;
#pragma unroll
    for (int e2 = 0; e2 < 8; ++e2) s += expf(a[e2] - bm);
    const float p  = 1.f / s;
    const float l0 = a[8] + cb[0], l1 = a[9] + cb[1];
    const float mx = fmaxf(l0, l1);
    const float e0 = expf(l0 - mx), e1 = expf(l1 - mx);
    const float inv = 1.f / (e0 + e1);
    eidx[row] = best;
    s0[row]   = p * (e0 * inv);
    c1[row]   = e1 * inv;
    if (bm - sec < GAPTHR) {
      int fi = atomicAdd(nflag, 1);
      if (fi < MAXFLAG) flaglist[fi] = row;
    }
  }
}

// ----------------------------------------------------------------------------
// fixup1: zpart[kb][f][j] = sum_{k in 128-chunk kb} x[row_f][k] * enc_W[k][j]
// grid (16 jb, 16 kb, F1Z rs).  Disjoint W slabs per (jb,kb); row-batches
// striped over rs.  float4 LDS reads; f64 accum, order identical to R6
// (bit-identical output).  Deterministic (no atomics).
// ----------------------------------------------------------------------------
__global__ __launch_bounds__(256)
void fixup1_kernel(const float* __restrict__ x, const float* __restrict__ encW,
                   const int* __restrict__ flaglist, const int* __restrict__ nflag,
                   float* __restrict__ zpart)   // [16][MAXFLAG][HD]
{
  __shared__ float xs[8][128];
  __shared__ double red[8][4][64];
  int nf = *nflag; if (nf > MAXFLAG) nf = MAXFLAG;
  if (nf <= 0) return;
  const int t  = threadIdx.x;
  const int jb = blockIdx.x, kb = blockIdx.y, rs = blockIdx.z;
  const int tj = t & 63, tk = t >> 6;          // tk in [0,4)
  const int j  = jb * 64 + tj;
  const int k0 = kb * 128 + tk * 32;
  float w[32];
#pragma unroll
  for (int kk = 0; kk < 32; ++kk)
    w[kk] = encW[(size_t)(k0 + kk) * HD + j];

  const int nb = (nf + 7) >> 3;
  for (int fb = rs; fb < nb; fb += F1Z) {
    __syncthreads();                           // xs/red reuse across batches
    {
      const int r  = t >> 5;                   // 0..7
      const int kc = (t & 31) * 4;
      int f = fb * 8 + r; if (f > nf - 1) f = nf - 1;
      const int row = flaglist[f];
      *(float4*)&xs[r][kc] =
          *(const float4*)&x[(size_t)row * DIN + kb * 128 + kc];
    }
    __syncthreads();
    double acc[8];
#pragma unroll
    for (int r = 0; r < 8; ++r) acc[r] = 0.0;
#pragma unroll
    for (int kq = 0; kq < 8; ++kq) {           // float4 LDS reads (broadcast)
      float4 xv[8];
#pragma unroll
      for (int r = 0; r < 8; ++r)
        xv[r] = *(const float4*)&xs[r][tk * 32 + kq * 4];
#pragma unroll
      for (int r = 0; r < 8; ++r) {
        acc[r] += (double)xv[r].x * (double)w[kq * 4 + 0];
        acc[r] += (double)xv[r].y * (double)w[kq * 4 + 1];
        acc[r] += (double)xv[r].z * (double)w[kq * 4 + 2];
        acc[r] += (double)xv[r].w * (double)w[kq * 4 + 3];
      }
    }
#pragma unroll
    for (int r = 0; r < 8; ++r) red[r][tk][tj] = acc[r];
    __syncthreads();
#pragma unroll
    for (int p = 0; p < 2; ++p) {
      const int idx = p * 256 + t;
      const int r = idx >> 6, jj = idx & 63;
      const int f = fb * 8 + r;
      if (f < nf)
        zpart[((size_t)kb * MAXFLAG + f) * HD + jb * 64 + jj] =
            (float)((red[r][0][jj] + red[r][1][jj]) +
                    (red[r][2][jj] + red[r][3][jj]));
    }
  }
}

// ----------------------------------------------------------------------------
// fixup2: exact gate for flagged rows (16 k-partials); overwrites eidx/s0/c1.
// ----------------------------------------------------------------------------
__global__ __launch_bounds__(256)
void fixup2_kernel(const float* __restrict__ zpart, const float* __restrict__ encB,
                   const float* __restrict__ gW, const float* __restrict__ cW,
                   const float* __restrict__ cb, const int* __restrict__ flaglist,
                   const int* __restrict__ nflag, int* __restrict__ eidx,
                   float* __restrict__ s0, float* __restrict__ c1)
{
  __shared__ double red[4][10];
  int nf = *nflag; if (nf > MAXFLAG) nf = MAXFLAG;
  const int t = threadIdx.x, lane = t & 63, w = t >> 6;
  for (int f = blockIdx.x; f < nf; f += 128) {
    const int row = flaglist[f];
    double part[10];
#pragma unroll
    for (int i = 0; i < 10; ++i) part[i] = 0.0;
    for (int jj = t; jj < HD; jj += 256) {
      double z = 0.0;
#pragma unroll
      for (int kb = 0; kb < 16; ++kb)
        z += (double)zpart[((size_t)kb * MAXFLAG + f) * HD + jj];
      double hj = z + (double)encB[jj];
      hj = hj > 0.0 ? hj : 0.0;
      const float* gr = gW + (size_t)jj * 8;
#pragma unroll
      for (int e2 = 0; e2 < 8; ++e2) part[e2] += hj * (double)gr[e2];
      part[8] += hj * (double)cW[jj * 2];
      part[9] += hj * (double)cW[jj * 2 + 1];
    }
#pragma unroll
    for (int off = 32; off > 0; off >>= 1)
#pragma unroll
      for (int i = 0; i < 10; ++i) part[i] += __shfl_xor(part[i], off);
    if (lane == 0)
#pragma unroll
      for (int i = 0; i < 10; ++i) red[w][i] = part[i];
    __syncthreads();
    if (t == 0) {
      double a[10];
#pragma unroll
      for (int i = 0; i < 10; ++i)
        a[i] = red[0][i] + red[1][i] + red[2][i] + red[3][i];
      int best = 0; double bm = a[0];
#pragma unroll
      for (int e2 = 1; e2 < 8; ++e2) if (a[e2] > bm) { bm = a[e2]; best = e2; }
      double s = 0.0;
#pragma unroll
      for (int e2 = 0; e2 < 8; ++e2) s += exp(a[e2] - bm);
      const double p  = 1.0 / s;
      const double l0 = a[8] + (double)cb[0], l1 = a[9] + (double)cb[1];
      const double mx = l0 > l1 ? l0 : l1;
      const double e0 = exp(l0 - mx), e1 = exp(l1 - mx);
      const double inv = 1.0 / (e0 + e1);
      eidx[row] = best;
      s0[row]   = (float)(p * e0 * inv);
      c1[row]   = (float)(e1 * inv);
    }
    __syncthreads();
  }
}

__global__ __launch_bounds__(256)
void count_kernel(const int* __restrict__ eidx, unsigned* __restrict__ cnt) {
  const int n = blockIdx.x * 256 + threadIdx.x;
  atomicAdd(&cnt[eidx[n]], 1u);
}

__global__ void scan_kernel(const unsigned* __restrict__ cnt,
                            int* __restrict__ tinfo, int* __restrict__ offs,
                            int* __restrict__ cursor) {
  if (threadIdx.x == 0 && blockIdx.x == 0) {
    int off = 0, nt = 0;
    for (int e = 0; e < NEXP; ++e) {
      offs[e] = off; cursor[e] = 0;
      const int c = (int)cnt[e];
      const int end = off + c;
      for (int r = 0; r < c; r += 128) {
        tinfo[1 + nt * 3 + 0] = e;
        tinfo[1 + nt * 3 + 1] = off + r;
        tinfo[1 + nt * 3 + 2] = end;
        ++nt;
      }
      off = end;
    }
    tinfo[0] = nt;
  }
}

__global__ __launch_bounds__(256)
void scatter_kernel(const int* __restrict__ eidx, const int* __restrict__ offs,
                    int* __restrict__ cursor, int* __restrict__ rowperm) {
  const int n = blockIdx.x * 256 + threadIdx.x;
  const int e = eidx[n];
  rowperm[offs[e] + atomicAdd(&cursor[e], 1)] = n;
}

// ----------------------------------------------------------------------------
extern "C" void kernel_launch(void* const* d_in, const int* in_sizes, int n_in,
                              void* d_out, int out_size, void* d_ws, size_t ws_size,
                              hipStream_t stream) {
  (void)in_sizes; (void)n_in; (void)out_size;
  const float* x      = (const float*)d_in[0];
  const float* enc_W  = (const float*)d_in[1];
  const float* enc_b  = (const float*)d_in[2];
  const float* gate_W = (const float*)d_in[3];
  const float* exp_W  = (const float*)d_in[4];
  const float* exp_b  = (const float*)d_in[5];
  const float* mlp_W  = (const float*)d_in[6];
  const float* mlp_b  = (const float*)d_in[7];
  const float* coef_W = (const float*)d_in[8];
  const float* coef_b = (const float*)d_in[9];
  const float* dec_W  = (const float*)d_in[10];
  const float* dec_b  = (const float*)d_in[11];

  char* ws = (char*)d_ws;
  size_t off = 0;
  auto alloc = [&](size_t bytes) {
    char* p = ws + off;
    off += (bytes + 255) & ~(size_t)255;
    return p;
  };
  uint16_t* encWT  = (uint16_t*)alloc((size_t)DIN * HD * 2);          //  4 MiB
  uint16_t* mlpWT  = (uint16_t*)alloc((size_t)HD * HD * 2);           //  2 MiB
  uint16_t* decWT  = (uint16_t*)alloc((size_t)HD * DIN * 2);          //  4 MiB
  uint16_t* expWT  = (uint16_t*)alloc((size_t)NEXP * HD * HD * 2);    // 16 MiB
  uint16_t* h_bf   = (uint16_t*)alloc((size_t)NROWS * HD * 2);        // 16 MiB
  float*    zpart  = (float*)   alloc((size_t)16 * MAXFLAG * HD * 4); // 32 MiB
  int*      eidx   = (int*)     alloc(NROWS * 4);
  float*    s0     = (float*)   alloc(NROWS * 4);
  float*    c1     = (float*)   alloc(NROWS * 4);
  int*      rowperm= (int*)     alloc(NROWS * 4);
  int*      flags  = (int*)     alloc(MAXFLAG * 4);
  char*     ctrs   = (char*)    alloc(256);
  int*      offs   = (int*)     alloc(64);
  int*      cursor = (int*)     alloc(64);
  int*      tinfo  = (int*)     alloc((1 + MAX_TILES * 3) * 4 + 64);
  // accout aliases zpart: zpart dead after fixup2; expert GEMM then writes
  // every element of accout before mlp/dec read it.
  uint16_t* accout = (uint16_t*)zpart;
  unsigned* cnt    = (unsigned*)ctrs;
  int*      nflag  = (int*)(ctrs + 32);
  if (off > ws_size) return;

  hipMemsetAsync(ctrs, 0, 256, stream);

  const dim3 blk(256);
  tcast_k<<<dim3(HD / 64, DIN / 64, 1),    blk, 0, stream>>>(enc_W, encWT, DIN, HD);
  tcast_k<<<dim3(HD / 64, HD / 64, 1),     blk, 0, stream>>>(mlp_W, mlpWT, HD, HD);
  tcast_k<<<dim3(DIN / 64, HD / 64, 1),    blk, 0, stream>>>(dec_W, decWT, HD, DIN);
  tcast_k<<<dim3(HD / 64, HD / 64, NEXP),  blk, 0, stream>>>(exp_W, expWT, HD, HD);

  gemm_kernel<0><<<dim3(NROWS / 128, HD / 128), blk, 0, stream>>>(
      x, encWT, h_bf, nullptr, enc_b, nullptr, nullptr, nullptr,
      NROWS, HD, DIN);

  gate_kernel<<<dim3(NROWS / 4), blk, 0, stream>>>(
      h_bf, gate_W, coef_W, coef_b, eidx, s0, c1, nflag, flags);
  fixup1_kernel<<<dim3(16, 16, F1Z), blk, 0, stream>>>(x, enc_W, flags, nflag, zpart);
  fixup2_kernel<<<dim3(128), blk, 0, stream>>>(
      zpart, enc_b, gate_W, coef_W, coef_b, flags, nflag, eidx, s0, c1);

  count_kernel<<<dim3(NROWS / 256), blk, 0, stream>>>(eidx, cnt);
  scan_kernel<<<1, 64, 0, stream>>>(cnt, tinfo, offs, cursor);
  scatter_kernel<<<dim3(NROWS / 256), blk, 0, stream>>>(eidx, offs, cursor, rowperm);

  gemm_kernel<1><<<dim3(MAX_TILES, HD / 128), blk, 0, stream>>>(
      h_bf, expWT, accout, nullptr, exp_b, rowperm, tinfo, s0,
      NROWS, HD, HD);
  gemm_kernel<2><<<dim3(NROWS / 128, HD / 128), blk, 0, stream>>>(
      h_bf, mlpWT, accout, nullptr, mlp_b, nullptr, nullptr, c1,
      NROWS, HD, HD);
  gemm_kernel<3><<<dim3(NROWS / 128, DIN / 128), blk, 0, stream>>>(
      accout, decWT, nullptr, (float*)d_out, dec_b, nullptr, nullptr, nullptr,
      NROWS, DIN, HD);
}

// Round 8
// 419.844 us; speedup vs baseline: 1.8492x; 1.0239x over previous
//
#include <hip/hip_runtime.h>
#include <hip/hip_bf16.h>
#include <stdint.h>

// ============================================================================
// MoE Autoencoder (N=8192, D_IN=2048, H=1024, E=8).  f32 in / f32 out,
// bf16-tolerance (0.0625) => bf16 MFMA compute.
// Round 8:
//   - x pre-cast to bf16 (aliases zpart; lifetime-disjoint) -> enc GEMM uses
//     pure global_load_lds path; A traffic halves; no in-loop VALU cast.
//   - XCD swizzle flipped to mtile-major chunks (A-panel L2 reuse; R7 grouped
//     by B-panel which was backwards for A>>B shapes).
// ============================================================================

using bf16 = __hip_bfloat16;
typedef __bf16 bf16x8 __attribute__((ext_vector_type(8)));
typedef float f32x4 __attribute__((ext_vector_type(4)));

static constexpr int NROWS = 8192;
static constexpr int DIN   = 2048;
static constexpr int HD    = 1024;
static constexpr int NEXP  = 8;
static constexpr int MAX_TILES = 72;     // sum_e ceil(cnt_e/128) <= 64+7
static constexpr int MAXFLAG = 512;      // measured nf ~ 345
static constexpr int F1Z = 7;            // fixup1 row-split (blocks/CU)
#define GAPTHR 0.02f

__device__ __forceinline__ uint16_t f2u(float f) {
  bf16 h = __float2bfloat16(f);
  uint16_t u; __builtin_memcpy(&u, &h, 2); return u;
}
__device__ __forceinline__ float u2f(uint16_t u) {
  uint32_t x = ((uint32_t)u) << 16;
  float f; __builtin_memcpy(&f, &x, 4); return f;
}

typedef const __attribute__((address_space(1))) void* gas_ptr;
typedef __attribute__((address_space(3))) void* las_ptr;
__device__ __forceinline__ void async16(void* lds, const void* g) {
  __builtin_amdgcn_global_load_lds((gas_ptr)g, (las_ptr)lds, 16, 0, 0);
}

// ----------------------------------------------------------------------------
// Elementwise cast f32 -> bf16 (8 elems/thread, vectorized).
// ----------------------------------------------------------------------------
__global__ __launch_bounds__(256)
void cast_k(const float* __restrict__ in, uint16_t* __restrict__ out, int n8) {
  const int stride = gridDim.x * 256;
  for (int i = blockIdx.x * 256 + threadIdx.x; i < n8; i += stride) {
    const float* s = in + (size_t)i * 8;
    float4 v0 = *(const float4*)(s);
    float4 v1 = *(const float4*)(s + 4);
    uint16_t tmp[8];
    tmp[0] = f2u(v0.x); tmp[1] = f2u(v0.y); tmp[2] = f2u(v0.z); tmp[3] = f2u(v0.w);
    tmp[4] = f2u(v1.x); tmp[5] = f2u(v1.y); tmp[6] = f2u(v1.z); tmp[7] = f2u(v1.w);
    int4 pv; __builtin_memcpy(&pv, tmp, 16);
    *(int4*)(out + (size_t)i * 8) = pv;
  }
}

// ----------------------------------------------------------------------------
// 64x64-tile transpose + cast f32 -> bf16: out[C][R] = bf16(in[R][C]).
// ----------------------------------------------------------------------------
__global__ __launch_bounds__(256)
void tcast_k(const float* __restrict__ in, uint16_t* __restrict__ out,
             int R, int C) {
  __shared__ float tile[64 * 65];
  const int t  = threadIdx.x;
  const int C0 = blockIdx.x * 64, R0 = blockIdx.y * 64;
  in  += (size_t)blockIdx.z * R * C;
  out += (size_t)blockIdx.z * R * C;
  const int cl = (t & 7) * 8;
#pragma unroll
  for (int p = 0; p < 2; ++p) {
    const int r = p * 32 + (t >> 3);
    const float* src = in + (size_t)(R0 + r) * C + C0 + cl;
    float4 v0 = *(const float4*)(src);
    float4 v1 = *(const float4*)(src + 4);
    float* dst = &tile[r * 65 + cl];
    dst[0] = v0.x; dst[1] = v0.y; dst[2] = v0.z; dst[3] = v0.w;
    dst[4] = v1.x; dst[5] = v1.y; dst[6] = v1.z; dst[7] = v1.w;
  }
  __syncthreads();
#pragma unroll
  for (int p = 0; p < 2; ++p) {
    const int oc = p * 32 + (t >> 3);
    uint16_t tmp[8];
#pragma unroll
    for (int j = 0; j < 8; ++j) tmp[j] = f2u(tile[(cl + j) * 65 + oc]);
    int4 v; __builtin_memcpy(&v, tmp, 16);
    *(int4*)(out + (size_t)(C0 + oc) * R + R0 + cl) = v;
  }
}

// ----------------------------------------------------------------------------
// 128x128-tile GEMM, BK=64, 4 waves:  C = epilogue(A[M,K] @ BT[N,K]^T)
// All A inputs bf16 now; pure global_load_lds staging.
// XCD swizzle: mtile-major chunks — each XCD walks one mtile's full ntile
// range consecutively => A-panel stays in that XCD's L2.
// MODE 0: enc  — relu(acc+b) -> C16 (bf16)
// MODE 1: exp  — gathered rows; (acc + b_e) * scale[orig], scattered (bf16)
// MODE 2: mlp  — C16[r,c] += (acc + b) * scale[r]         (bf16 RMW)
// MODE 3: dec  — C32 = acc + b                            (f32 out)
// ----------------------------------------------------------------------------
template<int MODE>
__global__ __launch_bounds__(256)
void gemm_kernel(const uint16_t* __restrict__ A, const uint16_t* __restrict__ BT,
                 uint16_t* __restrict__ C16, float* __restrict__ C32,
                 const float* __restrict__ biasf,
                 const int* __restrict__ rowperm, const int* __restrict__ tinfo,
                 const float* __restrict__ scale, int M, int N, int K)
{
  const int t = threadIdx.x;
  // T1 swizzle, mtile-major: hw linear id -> per-XCD contiguous tile chunk,
  // tile index enumerated with ntile fastest (A-panel reuse within chunk).
  const int nty = gridDim.y;
  const int nwg = gridDim.x * nty;
  const int hwf = blockIdx.y * gridDim.x + blockIdx.x;
  const int swz = (hwf & 7) * (nwg >> 3) + (hwf >> 3);
  const int mtile = swz / nty;
  const int ntile = swz % nty;

  int e = 0, row0 = 0, rowend = 0;
  if constexpr (MODE == 1) {
    const int nt = tinfo[0];
    if (mtile >= nt) return;
    e      = tinfo[1 + mtile * 3 + 0];
    row0   = tinfo[1 + mtile * 3 + 1];
    rowend = tinfo[1 + mtile * 3 + 2];
  }

  __shared__ uint16_t As[128 * 64];
  __shared__ uint16_t Bs[128 * 64];

  const int kcol = (t & 7) * 8;
  const uint16_t* asrc[4];
  const uint16_t* bsrc[4];
#pragma unroll
  for (int c = 0; c < 4; ++c) {
    const int r = c * 32 + (t >> 3);
    int arow;
    if constexpr (MODE == 1) {
      int pr = row0 + r;
      if (pr > rowend - 1) pr = rowend - 1;     // pad rows clamped, masked later
      arow = rowperm[pr];
    } else {
      arow = mtile * 128 + r;
    }
    asrc[c] = A + (size_t)arow * K + kcol;
    size_t brow = (size_t)ntile * 128 + r;
    if constexpr (MODE == 1) brow += (size_t)e * N;   // expWT: [E][N][K]
    bsrc[c] = BT + brow * (size_t)K + kcol;
  }

  f32x4 acc[4][4];
  const f32x4 zero = {0.f, 0.f, 0.f, 0.f};
#pragma unroll
  for (int i = 0; i < 4; ++i)
#pragma unroll
    for (int j = 0; j < 4; ++j) acc[i][j] = zero;

  const int wid = t >> 6, lane = t & 63;
  const int wm = wid >> 1, wn = wid & 1;
  const int frow = lane & 15;
  const int fk = (lane >> 4) * 8;

  const int nk = K >> 6;
  for (int kt = 0; kt < nk; ++kt) {
#pragma unroll
    for (int c = 0; c < 4; ++c) {
      async16(&As[c * 2048 + t * 8], asrc[c] + kt * 64);
      async16(&Bs[c * 2048 + t * 8], bsrc[c] + kt * 64);
    }
    __syncthreads();
#pragma unroll
    for (int kk = 0; kk < 2; ++kk) {
      bf16x8 af[4], bfr[4];
#pragma unroll
      for (int mi = 0; mi < 4; ++mi)
        af[mi] = *reinterpret_cast<const bf16x8*>(
            &As[(wm * 64 + mi * 16 + frow) * 64 + kk * 32 + fk]);
#pragma unroll
      for (int ni = 0; ni < 4; ++ni)
        bfr[ni] = *reinterpret_cast<const bf16x8*>(
            &Bs[(wn * 64 + ni * 16 + frow) * 64 + kk * 32 + fk]);
#pragma unroll
      for (int mi = 0; mi < 4; ++mi)
#pragma unroll
        for (int ni = 0; ni < 4; ++ni)
          acc[mi][ni] = __builtin_amdgcn_mfma_f32_16x16x32_bf16(
              af[mi], bfr[ni], acc[mi][ni], 0, 0, 0);
    }
    __syncthreads();
  }

  // epilogue — C/D layout: col = lane&15, row = (lane>>4)*4 + j   [m89]
  const int nbase = ntile * 128 + wn * 64;
  const int rbase = wm * 64 + (lane >> 4) * 4;
  const int cbase = lane & 15;
#pragma unroll
  for (int mi = 0; mi < 4; ++mi) {
#pragma unroll
    for (int j = 0; j < 4; ++j) {
      const int rr = rbase + mi * 16 + j;
      if constexpr (MODE == 1) {
        const int pr = row0 + rr;
        if (pr < rowend) {
          const int orig = rowperm[pr];
          const float sc = scale[orig];
          uint16_t* dst = C16 + (size_t)orig * N;
#pragma unroll
          for (int ni = 0; ni < 4; ++ni) {
            const int gc = nbase + ni * 16 + cbase;
            dst[gc] = f2u((acc[mi][ni][j] + biasf[e * N + gc]) * sc);
          }
        }
      } else {
        const int gr = mtile * 128 + rr;
#pragma unroll
        for (int ni = 0; ni < 4; ++ni) {
          const int gc = nbase + ni * 16 + cbase;
          float v = acc[mi][ni][j] + biasf[gc];
          if constexpr (MODE == 0) {
            C16[(size_t)gr * N + gc] = f2u(fmaxf(v, 0.f));
          } else if constexpr (MODE == 2) {
            const float prev = u2f(C16[(size_t)gr * N + gc]);
            C16[(size_t)gr * N + gc] = f2u(prev + v * scale[gr]);
          } else {
            C32[(size_t)gr * N + gc] = v;
          }
        }
      }
    }
  }
}

// ----------------------------------------------------------------------------
// Gate from bf16 h: logits = h @ gate_W, coef = softmax(h @ coef_W + cb).
// One wave per row; flags rows with top2 gap < GAPTHR for exact fixup.
// ----------------------------------------------------------------------------
__global__ __launch_bounds__(256)
void gate_kernel(const uint16_t* __restrict__ hbf, const float* __restrict__ gW,
                 const float* __restrict__ cW, const float* __restrict__ cb,
                 int* __restrict__ eidx, float* __restrict__ s0,
                 float* __restrict__ c1, int* __restrict__ nflag,
                 int* __restrict__ flaglist)
{
  const int lane = threadIdx.x & 63;
  const int row  = blockIdx.x * 4 + (threadIdx.x >> 6);
  const uint16_t* hrow = hbf + (size_t)row * HD;
  float a[10];
#pragma unroll
  for (int i = 0; i < 10; ++i) a[i] = 0.f;
  for (int kk = 0; kk < HD / 64; ++kk) {
    const int k = kk * 64 + lane;
    const float hv = u2f(hrow[k]);
    float4 g0 = *(const float4*)(gW + (size_t)k * 8);
    float4 g1 = *(const float4*)(gW + (size_t)k * 8 + 4);
    a[0] += hv * g0.x; a[1] += hv * g0.y; a[2] += hv * g0.z; a[3] += hv * g0.w;
    a[4] += hv * g1.x; a[5] += hv * g1.y; a[6] += hv * g1.z; a[7] += hv * g1.w;
    float2 cv = *(const float2*)(cW + (size_t)k * 2);
    a[8] += hv * cv.x; a[9] += hv * cv.y;
  }
#pragma unroll
  for (int off = 32; off > 0; off >>= 1) {
#pragma unroll
    for (int i = 0; i < 10; ++i) a[i] += __shfl_xor(a[i], off);
  }
  if (lane == 0) {
    int best = 0; float bm = a[0];
#pragma unroll
    for (int e2 = 1; e2 < 8; ++e2) if (a[e2] > bm) { bm = a[e2]; best = e2; }
    float sec = -3.0e38f;
#pragma unroll
    for (int e2 = 0; e2 < 8; ++e2) if (e2 != best) sec = fmaxf(sec, a[e2]);
    float s = 0.f;
#pragma unroll
    for (int e2 = 0; e2 < 8; ++e2) s += expf(a[e2] - bm);
    const float p  = 1.f / s;
    const float l0 = a[8] + cb[0], l1 = a[9] + cb[1];
    const float mx = fmaxf(l0, l1);
    const float e0 = expf(l0 - mx), e1 = expf(l1 - mx);
    const float inv = 1.f / (e0 + e1);
    eidx[row] = best;
    s0[row]   = p * (e0 * inv);
    c1[row]   = e1 * inv;
    if (bm - sec < GAPTHR) {
      int fi = atomicAdd(nflag, 1);
      if (fi < MAXFLAG) flaglist[fi] = row;
    }
  }
}

// ----------------------------------------------------------------------------
// fixup1: zpart[kb][f][j] = sum_{k in 128-chunk kb} x[row_f][k] * enc_W[k][j]
// grid (16 jb, 16 kb, F1Z rs).  Disjoint W slabs per (jb,kb); row-batches
// striped over rs.  float4 LDS reads; f64 accum.  Deterministic.
// ----------------------------------------------------------------------------
__global__ __launch_bounds__(256)
void fixup1_kernel(const float* __restrict__ x, const float* __restrict__ encW,
                   const int* __restrict__ flaglist, const int* __restrict__ nflag,
                   float* __restrict__ zpart)   // [16][MAXFLAG][HD]
{
  __shared__ float xs[8][128];
  __shared__ double red[8][4][64];
  int nf = *nflag; if (nf > MAXFLAG) nf = MAXFLAG;
  if (nf <= 0) return;
  const int t  = threadIdx.x;
  const int jb = blockIdx.x, kb = blockIdx.y, rs = blockIdx.z;
  const int tj = t & 63, tk = t >> 6;          // tk in [0,4)
  const int j  = jb * 64 + tj;
  const int k0 = kb * 128 + tk * 32;
  float w[32];
#pragma unroll
  for (int kk = 0; kk < 32; ++kk)
    w[kk] = encW[(size_t)(k0 + kk) * HD + j];

  const int nb = (nf + 7) >> 3;
  for (int fb = rs; fb < nb; fb += F1Z) {
    __syncthreads();                           // xs/red reuse across batches
    {
      const int r  = t >> 5;                   // 0..7
      const int kc = (t & 31) * 4;
      int f = fb * 8 + r; if (f > nf - 1) f = nf - 1;
      const int row = flaglist[f];
      *(float4*)&xs[r][kc] =
          *(const float4*)&x[(size_t)row * DIN + kb * 128 + kc];
    }
    __syncthreads();
    double acc[8];
#pragma unroll
    for (int r = 0; r < 8; ++r) acc[r] = 0.0;
#pragma unroll
    for (int kq = 0; kq < 8; ++kq) {           // float4 LDS reads (broadcast)
      float4 xv[8];
#pragma unroll
      for (int r = 0; r < 8; ++r)
        xv[r] = *(const float4*)&xs[r][tk * 32 + kq * 4];
#pragma unroll
      for (int r = 0; r < 8; ++r) {
        acc[r] += (double)xv[r].x * (double)w[kq * 4 + 0];
        acc[r] += (double)xv[r].y * (double)w[kq * 4 + 1];
        acc[r] += (double)xv[r].z * (double)w[kq * 4 + 2];
        acc[r] += (double)xv[r].w * (double)w[kq * 4 + 3];
      }
    }
#pragma unroll
    for (int r = 0; r < 8; ++r) red[r][tk][tj] = acc[r];
    __syncthreads();
#pragma unroll
    for (int p = 0; p < 2; ++p) {
      const int idx = p * 256 + t;
      const int r = idx >> 6, jj = idx & 63;
      const int f = fb * 8 + r;
      if (f < nf)
        zpart[((size_t)kb * MAXFLAG + f) * HD + jb * 64 + jj] =
            (float)((red[r][0][jj] + red[r][1][jj]) +
                    (red[r][2][jj] + red[r][3][jj]));
    }
  }
}

// ----------------------------------------------------------------------------
// fixup2: exact gate for flagged rows (16 k-partials); overwrites eidx/s0/c1.
// ----------------------------------------------------------------------------
__global__ __launch_bounds__(256)
void fixup2_kernel(const float* __restrict__ zpart, const float* __restrict__ encB,
                   const float* __restrict__ gW, const float* __restrict__ cW,
                   const float* __restrict__ cb, const int* __restrict__ flaglist,
                   const int* __restrict__ nflag, int* __restrict__ eidx,
                   float* __restrict__ s0, float* __restrict__ c1)
{
  __shared__ double red[4][10];
  int nf = *nflag; if (nf > MAXFLAG) nf = MAXFLAG;
  const int t = threadIdx.x, lane = t & 63, w = t >> 6;
  for (int f = blockIdx.x; f < nf; f += 128) {
    const int row = flaglist[f];
    double part[10];
#pragma unroll
    for (int i = 0; i < 10; ++i) part[i] = 0.0;
    for (int jj = t; jj < HD; jj += 256) {
      double z = 0.0;
#pragma unroll
      for (int kb = 0; kb < 16; ++kb)
        z += (double)zpart[((size_t)kb * MAXFLAG + f) * HD + jj];
      double hj = z + (double)encB[jj];
      hj = hj > 0.0 ? hj : 0.0;
      const float* gr = gW + (size_t)jj * 8;
#pragma unroll
      for (int e2 = 0; e2 < 8; ++e2) part[e2] += hj * (double)gr[e2];
      part[8] += hj * (double)cW[jj * 2];
      part[9] += hj * (double)cW[jj * 2 + 1];
    }
#pragma unroll
    for (int off = 32; off > 0; off >>= 1)
#pragma unroll
      for (int i = 0; i < 10; ++i) part[i] += __shfl_xor(part[i], off);
    if (lane == 0)
#pragma unroll
      for (int i = 0; i < 10; ++i) red[w][i] = part[i];
    __syncthreads();
    if (t == 0) {
      double a[10];
#pragma unroll
      for (int i = 0; i < 10; ++i)
        a[i] = red[0][i] + red[1][i] + red[2][i] + red[3][i];
      int best = 0; double bm = a[0];
#pragma unroll
      for (int e2 = 1; e2 < 8; ++e2) if (a[e2] > bm) { bm = a[e2]; best = e2; }
      double s = 0.0;
#pragma unroll
      for (int e2 = 0; e2 < 8; ++e2) s += exp(a[e2] - bm);
      const double p  = 1.0 / s;
      const double l0 = a[8] + (double)cb[0], l1 = a[9] + (double)cb[1];
      const double mx = l0 > l1 ? l0 : l1;
      const double e0 = exp(l0 - mx), e1 = exp(l1 - mx);
      const double inv = 1.0 / (e0 + e1);
      eidx[row] = best;
      s0[row]   = (float)(p * e0 * inv);
      c1[row]   = (float)(e1 * inv);
    }
    __syncthreads();
  }
}

__global__ __launch_bounds__(256)
void count_kernel(const int* __restrict__ eidx, unsigned* __restrict__ cnt) {
  const int n = blockIdx.x * 256 + threadIdx.x;
  atomicAdd(&cnt[eidx[n]], 1u);
}

__global__ void scan_kernel(const unsigned* __restrict__ cnt,
                            int* __restrict__ tinfo, int* __restrict__ offs,
                            int* __restrict__ cursor) {
  if (threadIdx.x == 0 && blockIdx.x == 0) {
    int off = 0, nt = 0;
    for (int e = 0; e < NEXP; ++e) {
      offs[e] = off; cursor[e] = 0;
      const int c = (int)cnt[e];
      const int end = off + c;
      for (int r = 0; r < c; r += 128) {
        tinfo[1 + nt * 3 + 0] = e;
        tinfo[1 + nt * 3 + 1] = off + r;
        tinfo[1 + nt * 3 + 2] = end;
        ++nt;
      }
      off = end;
    }
    tinfo[0] = nt;
  }
}

__global__ __launch_bounds__(256)
void scatter_kernel(const int* __restrict__ eidx, const int* __restrict__ offs,
                    int* __restrict__ cursor, int* __restrict__ rowperm) {
  const int n = blockIdx.x * 256 + threadIdx.x;
  const int e = eidx[n];
  rowperm[offs[e] + atomicAdd(&cursor[e], 1)] = n;
}

// ----------------------------------------------------------------------------
extern "C" void kernel_launch(void* const* d_in, const int* in_sizes, int n_in,
                              void* d_out, int out_size, void* d_ws, size_t ws_size,
                              hipStream_t stream) {
  (void)in_sizes; (void)n_in; (void)out_size;
  const float* x      = (const float*)d_in[0];
  const float* enc_W  = (const float*)d_in[1];
  const float* enc_b  = (const float*)d_in[2];
  const float* gate_W = (const float*)d_in[3];
  const float* exp_W  = (const float*)d_in[4];
  const float* exp_b  = (const float*)d_in[5];
  const float* mlp_W  = (const float*)d_in[6];
  const float* mlp_b  = (const float*)d_in[7];
  const float* coef_W = (const float*)d_in[8];
  const float* coef_b = (const float*)d_in[9];
  const float* dec_W  = (const float*)d_in[10];
  const float* dec_b  = (const float*)d_in[11];

  char* ws = (char*)d_ws;
  size_t off = 0;
  auto alloc = [&](size_t bytes) {
    char* p = ws + off;
    off += (bytes + 255) & ~(size_t)255;
    return p;
  };
  uint16_t* encWT  = (uint16_t*)alloc((size_t)DIN * HD * 2);          //  4 MiB
  uint16_t* mlpWT  = (uint16_t*)alloc((size_t)HD * HD * 2);           //  2 MiB
  uint16_t* decWT  = (uint16_t*)alloc((size_t)HD * DIN * 2);          //  4 MiB
  uint16_t* expWT  = (uint16_t*)alloc((size_t)NEXP * HD * HD * 2);    // 16 MiB
  uint16_t* h_bf   = (uint16_t*)alloc((size_t)NROWS * HD * 2);        // 16 MiB
  float*    zpart  = (float*)   alloc((size_t)16 * MAXFLAG * HD * 4); // 32 MiB
  int*      eidx   = (int*)     alloc(NROWS * 4);
  float*    s0     = (float*)   alloc(NROWS * 4);
  float*    c1     = (float*)   alloc(NROWS * 4);
  int*      rowperm= (int*)     alloc(NROWS * 4);
  int*      flags  = (int*)     alloc(MAXFLAG * 4);
  char*     ctrs   = (char*)    alloc(256);
  int*      offs   = (int*)     alloc(64);
  int*      cursor = (int*)     alloc(64);
  int*      tinfo  = (int*)     alloc((1 + MAX_TILES * 3) * 4 + 64);
  // Lifetime-disjoint aliases of the zpart region (33.55 MiB):
  //   x_bf  [cast, enc GEMM)        — NROWS*DIN*2 = 33.55 MiB
  //   zpart [fixup1, fixup2)        — 16*MAXFLAG*HD*4 = 33.55 MiB
  //   accout[exp GEMM, dec GEMM)    — NROWS*HD*2 = 16.78 MiB
  uint16_t* x_bf   = (uint16_t*)zpart;
  uint16_t* accout = (uint16_t*)zpart;
  unsigned* cnt    = (unsigned*)ctrs;
  int*      nflag  = (int*)(ctrs + 32);
  if (off > ws_size) return;

  hipMemsetAsync(ctrs, 0, 256, stream);

  const dim3 blk(256);
  cast_k<<<dim3(1024), blk, 0, stream>>>(x, x_bf, NROWS * DIN / 8);
  tcast_k<<<dim3(HD / 64, DIN / 64, 1),    blk, 0, stream>>>(enc_W, encWT, DIN, HD);
  tcast_k<<<dim3(HD / 64, HD / 64, 1),     blk, 0, stream>>>(mlp_W, mlpWT, HD, HD);
  tcast_k<<<dim3(DIN / 64, HD / 64, 1),    blk, 0, stream>>>(dec_W, decWT, HD, DIN);
  tcast_k<<<dim3(HD / 64, HD / 64, NEXP),  blk, 0, stream>>>(exp_W, expWT, HD, HD);

  gemm_kernel<0><<<dim3(NROWS / 128, HD / 128), blk, 0, stream>>>(
      x_bf, encWT, h_bf, nullptr, enc_b, nullptr, nullptr, nullptr,
      NROWS, HD, DIN);

  gate_kernel<<<dim3(NROWS / 4), blk, 0, stream>>>(
      h_bf, gate_W, coef_W, coef_b, eidx, s0, c1, nflag, flags);
  fixup1_kernel<<<dim3(16, 16, F1Z), blk, 0, stream>>>(x, enc_W, flags, nflag, zpart);
  fixup2_kernel<<<dim3(128), blk, 0, stream>>>(
      zpart, enc_b, gate_W, coef_W, coef_b, flags, nflag, eidx, s0, c1);

  count_kernel<<<dim3(NROWS / 256), blk, 0, stream>>>(eidx, cnt);
  scan_kernel<<<1, 64, 0, stream>>>(cnt, tinfo, offs, cursor);
  scatter_kernel<<<dim3(NROWS / 256), blk, 0, stream>>>(eidx, offs, cursor, rowperm);

  gemm_kernel<1><<<dim3(MAX_TILES, HD / 128), blk, 0, stream>>>(
      h_bf, expWT, accout, nullptr, exp_b, rowperm, tinfo, s0,
      NROWS, HD, HD);
  gemm_kernel<2><<<dim3(NROWS / 128, HD / 128), blk, 0, stream>>>(
      h_bf, mlpWT, accout, nullptr, mlp_b, nullptr, nullptr, c1,
      NROWS, HD, HD);
  gemm_kernel<3><<<dim3(NROWS / 128, DIN / 128), blk, 0, stream>>>(
      accout, decWT, nullptr, (float*)d_out, dec_b, nullptr, nullptr, nullptr,
      NROWS, DIN, HD);
}

// Round 9
// 411.074 us; speedup vs baseline: 1.8887x; 1.0213x over previous
//
#include <hip/hip_runtime.h>
#include <hip/hip_bf16.h>
#include <stdint.h>

// ============================================================================
// MoE Autoencoder (N=8192, D_IN=2048, H=1024, E=8).  f32 in / f32 out,
// bf16-tolerance (0.0625) => bf16 MFMA compute.
// Round 9: precision-cascaded gate fixup.
//   stage a: f32 row-GEMM for ~345 bf16-ambiguous rows (no cvt, 2cyc FMA),
//            re-flag rows with logit gap < 1e-3.
//   stage b: f64 row-GEMM for the ~20 survivors (exact arbiter).
//   Everything else unchanged from R8 (x precast, mtile-major XCD swizzle).
// ============================================================================

using bf16 = __hip_bfloat16;
typedef __bf16 bf16x8 __attribute__((ext_vector_type(8)));
typedef float f32x4 __attribute__((ext_vector_type(4)));

static constexpr int NROWS = 8192;
static constexpr int DIN   = 2048;
static constexpr int HD    = 1024;
static constexpr int NEXP  = 8;
static constexpr int MAX_TILES = 72;     // sum_e ceil(cnt_e/128) <= 64+7
static constexpr int MAXFLAG  = 512;     // stage-a capacity (measured nf ~345)
static constexpr int MAXFLAG2 = 128;     // stage-b capacity (expected ~20)
static constexpr int F1Z = 7;            // fixup1 row-split (blocks/CU)
#define GAPTHR  0.02f                    // bf16-logit ambiguity (≈10 sigma)
#define GAPTHR2 1.0e-3                   // f32-logit ambiguity  (≈300 sigma)

__device__ __forceinline__ uint16_t f2u(float f) {
  bf16 h = __float2bfloat16(f);
  uint16_t u; __builtin_memcpy(&u, &h, 2); return u;
}
__device__ __forceinline__ float u2f(uint16_t u) {
  uint32_t x = ((uint32_t)u) << 16;
  float f; __builtin_memcpy(&f, &x, 4); return f;
}

typedef const __attribute__((address_space(1))) void* gas_ptr;
typedef __attribute__((address_space(3))) void* las_ptr;
__device__ __forceinline__ void async16(void* lds, const void* g) {
  __builtin_amdgcn_global_load_lds((gas_ptr)g, (las_ptr)lds, 16, 0, 0);
}

// ----------------------------------------------------------------------------
// Elementwise cast f32 -> bf16 (8 elems/thread, vectorized).
// ----------------------------------------------------------------------------
__global__ __launch_bounds__(256)
void cast_k(const float* __restrict__ in, uint16_t* __restrict__ out, int n8) {
  const int stride = gridDim.x * 256;
  for (int i = blockIdx.x * 256 + threadIdx.x; i < n8; i += stride) {
    const float* s = in + (size_t)i * 8;
    float4 v0 = *(const float4*)(s);
    float4 v1 = *(const float4*)(s + 4);
    uint16_t tmp[8];
    tmp[0] = f2u(v0.x); tmp[1] = f2u(v0.y); tmp[2] = f2u(v0.z); tmp[3] = f2u(v0.w);
    tmp[4] = f2u(v1.x); tmp[5] = f2u(v1.y); tmp[6] = f2u(v1.z); tmp[7] = f2u(v1.w);
    int4 pv; __builtin_memcpy(&pv, tmp, 16);
    *(int4*)(out + (size_t)i * 8) = pv;
  }
}

// ----------------------------------------------------------------------------
// 64x64-tile transpose + cast f32 -> bf16: out[C][R] = bf16(in[R][C]).
// ----------------------------------------------------------------------------
__global__ __launch_bounds__(256)
void tcast_k(const float* __restrict__ in, uint16_t* __restrict__ out,
             int R, int C) {
  __shared__ float tile[64 * 65];
  const int t  = threadIdx.x;
  const int C0 = blockIdx.x * 64, R0 = blockIdx.y * 64;
  in  += (size_t)blockIdx.z * R * C;
  out += (size_t)blockIdx.z * R * C;
  const int cl = (t & 7) * 8;
#pragma unroll
  for (int p = 0; p < 2; ++p) {
    const int r = p * 32 + (t >> 3);
    const float* src = in + (size_t)(R0 + r) * C + C0 + cl;
    float4 v0 = *(const float4*)(src);
    float4 v1 = *(const float4*)(src + 4);
    float* dst = &tile[r * 65 + cl];
    dst[0] = v0.x; dst[1] = v0.y; dst[2] = v0.z; dst[3] = v0.w;
    dst[4] = v1.x; dst[5] = v1.y; dst[6] = v1.z; dst[7] = v1.w;
  }
  __syncthreads();
#pragma unroll
  for (int p = 0; p < 2; ++p) {
    const int oc = p * 32 + (t >> 3);
    uint16_t tmp[8];
#pragma unroll
    for (int j = 0; j < 8; ++j) tmp[j] = f2u(tile[(cl + j) * 65 + oc]);
    int4 v; __builtin_memcpy(&v, tmp, 16);
    *(int4*)(out + (size_t)(C0 + oc) * R + R0 + cl) = v;
  }
}

// ----------------------------------------------------------------------------
// 128x128-tile GEMM, BK=64, 4 waves:  C = epilogue(A[M,K] @ BT[N,K]^T)
// XCD swizzle, mtile-major chunks (A-panel L2 reuse).
// MODE 0: enc  — relu(acc+b) -> C16 (bf16)
// MODE 1: exp  — gathered rows; (acc + b_e) * scale[orig], scattered (bf16)
// MODE 2: mlp  — C16[r,c] += (acc + b) * scale[r]         (bf16 RMW)
// MODE 3: dec  — C32 = acc + b                            (f32 out)
// ----------------------------------------------------------------------------
template<int MODE>
__global__ __launch_bounds__(256)
void gemm_kernel(const uint16_t* __restrict__ A, const uint16_t* __restrict__ BT,
                 uint16_t* __restrict__ C16, float* __restrict__ C32,
                 const float* __restrict__ biasf,
                 const int* __restrict__ rowperm, const int* __restrict__ tinfo,
                 const float* __restrict__ scale, int M, int N, int K)
{
  const int t = threadIdx.x;
  const int nty = gridDim.y;
  const int nwg = gridDim.x * nty;
  const int hwf = blockIdx.y * gridDim.x + blockIdx.x;
  const int swz = (hwf & 7) * (nwg >> 3) + (hwf >> 3);
  const int mtile = swz / nty;
  const int ntile = swz % nty;

  int e = 0, row0 = 0, rowend = 0;
  if constexpr (MODE == 1) {
    const int nt = tinfo[0];
    if (mtile >= nt) return;
    e      = tinfo[1 + mtile * 3 + 0];
    row0   = tinfo[1 + mtile * 3 + 1];
    rowend = tinfo[1 + mtile * 3 + 2];
  }

  __shared__ uint16_t As[128 * 64];
  __shared__ uint16_t Bs[128 * 64];

  const int kcol = (t & 7) * 8;
  const uint16_t* asrc[4];
  const uint16_t* bsrc[4];
#pragma unroll
  for (int c = 0; c < 4; ++c) {
    const int r = c * 32 + (t >> 3);
    int arow;
    if constexpr (MODE == 1) {
      int pr = row0 + r;
      if (pr > rowend - 1) pr = rowend - 1;     // pad rows clamped, masked later
      arow = rowperm[pr];
    } else {
      arow = mtile * 128 + r;
    }
    asrc[c] = A + (size_t)arow * K + kcol;
    size_t brow = (size_t)ntile * 128 + r;
    if constexpr (MODE == 1) brow += (size_t)e * N;   // expWT: [E][N][K]
    bsrc[c] = BT + brow * (size_t)K + kcol;
  }

  f32x4 acc[4][4];
  const f32x4 zero = {0.f, 0.f, 0.f, 0.f};
#pragma unroll
  for (int i = 0; i < 4; ++i)
#pragma unroll
    for (int j = 0; j < 4; ++j) acc[i][j] = zero;

  const int wid = t >> 6, lane = t & 63;
  const int wm = wid >> 1, wn = wid & 1;
  const int frow = lane & 15;
  const int fk = (lane >> 4) * 8;

  const int nk = K >> 6;
  for (int kt = 0; kt < nk; ++kt) {
#pragma unroll
    for (int c = 0; c < 4; ++c) {
      async16(&As[c * 2048 + t * 8], asrc[c] + kt * 64);
      async16(&Bs[c * 2048 + t * 8], bsrc[c] + kt * 64);
    }
    __syncthreads();
#pragma unroll
    for (int kk = 0; kk < 2; ++kk) {
      bf16x8 af[4], bfr[4];
#pragma unroll
      for (int mi = 0; mi < 4; ++mi)
        af[mi] = *reinterpret_cast<const bf16x8*>(
            &As[(wm * 64 + mi * 16 + frow) * 64 + kk * 32 + fk]);
#pragma unroll
      for (int ni = 0; ni < 4; ++ni)
        bfr[ni] = *reinterpret_cast<const bf16x8*>(
            &Bs[(wn * 64 + ni * 16 + frow) * 64 + kk * 32 + fk]);
#pragma unroll
      for (int mi = 0; mi < 4; ++mi)
#pragma unroll
        for (int ni = 0; ni < 4; ++ni)
          acc[mi][ni] = __builtin_amdgcn_mfma_f32_16x16x32_bf16(
              af[mi], bfr[ni], acc[mi][ni], 0, 0, 0);
    }
    __syncthreads();
  }

  // epilogue — C/D layout: col = lane&15, row = (lane>>4)*4 + j   [m89]
  const int nbase = ntile * 128 + wn * 64;
  const int rbase = wm * 64 + (lane >> 4) * 4;
  const int cbase = lane & 15;
#pragma unroll
  for (int mi = 0; mi < 4; ++mi) {
#pragma unroll
    for (int j = 0; j < 4; ++j) {
      const int rr = rbase + mi * 16 + j;
      if constexpr (MODE == 1) {
        const int pr = row0 + rr;
        if (pr < rowend) {
          const int orig = rowperm[pr];
          const float sc = scale[orig];
          uint16_t* dst = C16 + (size_t)orig * N;
#pragma unroll
          for (int ni = 0; ni < 4; ++ni) {
            const int gc = nbase + ni * 16 + cbase;
            dst[gc] = f2u((acc[mi][ni][j] + biasf[e * N + gc]) * sc);
          }
        }
      } else {
        const int gr = mtile * 128 + rr;
#pragma unroll
        for (int ni = 0; ni < 4; ++ni) {
          const int gc = nbase + ni * 16 + cbase;
          float v = acc[mi][ni][j] + biasf[gc];
          if constexpr (MODE == 0) {
            C16[(size_t)gr * N + gc] = f2u(fmaxf(v, 0.f));
          } else if constexpr (MODE == 2) {
            const float prev = u2f(C16[(size_t)gr * N + gc]);
            C16[(size_t)gr * N + gc] = f2u(prev + v * scale[gr]);
          } else {
            C32[(size_t)gr * N + gc] = v;
          }
        }
      }
    }
  }
}

// ----------------------------------------------------------------------------
// Gate from bf16 h: logits = h @ gate_W, coef = softmax(h @ coef_W + cb).
// One wave per row; flags rows with top2 gap < GAPTHR for exact fixup.
// ----------------------------------------------------------------------------
__global__ __launch_bounds__(256)
void gate_kernel(const uint16_t* __restrict__ hbf, const float* __restrict__ gW,
                 const float* __restrict__ cW, const float* __restrict__ cb,
                 int* __restrict__ eidx, float* __restrict__ s0,
                 float* __restrict__ c1, int* __restrict__ nflag,
                 int* __restrict__ flaglist)
{
  const int lane = threadIdx.x & 63;
  const int row  = blockIdx.x * 4 + (threadIdx.x >> 6);
  const uint16_t* hrow = hbf + (size_t)row * HD;
  float a[10];
#pragma unroll
  for (int i = 0; i < 10; ++i) a[i] = 0.f;
  for (int kk = 0; kk < HD / 64; ++kk) {
    const int k = kk * 64 + lane;
    const float hv = u2f(hrow[k]);
    float4 g0 = *(const float4*)(gW + (size_t)k * 8);
    float4 g1 = *(const float4*)(gW + (size_t)k * 8 + 4);
    a[0] += hv * g0.x; a[1] += hv * g0.y; a[2] += hv * g0.z; a[3] += hv * g0.w;
    a[4] += hv * g1.x; a[5] += hv * g1.y; a[6] += hv * g1.z; a[7] += hv * g1.w;
    float2 cv = *(const float2*)(cW + (size_t)k * 2);
    a[8] += hv * cv.x; a[9] += hv * cv.y;
  }
#pragma unroll
  for (int off = 32; off > 0; off >>= 1) {
#pragma unroll
    for (int i = 0; i < 10; ++i) a[i] += __shfl_xor(a[i], off);
  }
  if (lane == 0) {
    int best = 0; float bm = a[0];
#pragma unroll
    for (int e2 = 1; e2 < 8; ++e2) if (a[e2] > bm) { bm = a[e2]; best = e2; }
    float sec = -3.0e38f;
#pragma unroll
    for (int e2 = 0; e2 < 8; ++e2) if (e2 != best) sec = fmaxf(sec, a[e2]);
    float s = 0.f;
#pragma unroll
    for (int e2 = 0; e2 < 8; ++e2) s += expf(a[e2] - bm);
    const float p  = 1.f / s;
    const float l0 = a[8] + cb[0], l1 = a[9] + cb[1];
    const float mx = fmaxf(l0, l1);
    const float e0 = expf(l0 - mx), e1 = expf(l1 - mx);
    const float inv = 1.f / (e0 + e1);
    eidx[row] = best;
    s0[row]   = p * (e0 * inv);
    c1[row]   = e1 * inv;
    if (bm - sec < GAPTHR) {
      int fi = atomicAdd(nflag, 1);
      if (fi < MAXFLAG) flaglist[fi] = row;
    }
  }
}

// ----------------------------------------------------------------------------
// fixup1<T>: zpart[kb][f][j] = sum_{k in 128-chunk kb} x[row_f][k]*enc_W[k][j]
// computed in T (float stage a / double stage b).  grid (16 jb, 16 kb, F1Z).
// Disjoint W slabs; row-batches striped over rs; deterministic.
// ----------------------------------------------------------------------------
template<typename T>
__global__ __launch_bounds__(256)
void fixup1_kernel(const float* __restrict__ x, const float* __restrict__ encW,
                   const int* __restrict__ flaglist, const int* __restrict__ nflag,
                   T* __restrict__ zpart, int fstride, int maxflag)
{
  __shared__ float xs[8][128];
  __shared__ T red[8][4][64];
  int nf = *nflag; if (nf > maxflag) nf = maxflag;
  if (nf <= 0) return;
  const int rs = blockIdx.z;
  const int nb = (nf + 7) >> 3;
  if (rs >= nb) return;                        // idle rs-blocks: skip W load
  const int t  = threadIdx.x;
  const int jb = blockIdx.x, kb = blockIdx.y;
  const int tj = t & 63, tk = t >> 6;          // tk in [0,4)
  const int j  = jb * 64 + tj;
  const int k0 = kb * 128 + tk * 32;
  float w[32];
#pragma unroll
  for (int kk = 0; kk < 32; ++kk)
    w[kk] = encW[(size_t)(k0 + kk) * HD + j];

  for (int fb = rs; fb < nb; fb += F1Z) {
    __syncthreads();                           // xs/red reuse across batches
    {
      const int r  = t >> 5;                   // 0..7
      const int kc = (t & 31) * 4;
      int f = fb * 8 + r; if (f > nf - 1) f = nf - 1;
      const int row = flaglist[f];
      *(float4*)&xs[r][kc] =
          *(const float4*)&x[(size_t)row * DIN + kb * 128 + kc];
    }
    __syncthreads();
    T acc[8];
#pragma unroll
    for (int r = 0; r < 8; ++r) acc[r] = (T)0;
#pragma unroll
    for (int kq = 0; kq < 8; ++kq) {           // float4 LDS reads (broadcast)
      float4 xv[8];
#pragma unroll
      for (int r = 0; r < 8; ++r)
        xv[r] = *(const float4*)&xs[r][tk * 32 + kq * 4];
#pragma unroll
      for (int r = 0; r < 8; ++r) {
        acc[r] += (T)xv[r].x * (T)w[kq * 4 + 0];
        acc[r] += (T)xv[r].y * (T)w[kq * 4 + 1];
        acc[r] += (T)xv[r].z * (T)w[kq * 4 + 2];
        acc[r] += (T)xv[r].w * (T)w[kq * 4 + 3];
      }
    }
#pragma unroll
    for (int r = 0; r < 8; ++r) red[r][tk][tj] = acc[r];
    __syncthreads();
#pragma unroll
    for (int p = 0; p < 2; ++p) {
      const int idx = p * 256 + t;
      const int r = idx >> 6, jj = idx & 63;
      const int f = fb * 8 + r;
      if (f < nf)
        zpart[((size_t)kb * fstride + f) * HD + jb * 64 + jj] =
            (red[r][0][jj] + red[r][1][jj]) + (red[r][2][jj] + red[r][3][jj]);
    }
  }
}

// ----------------------------------------------------------------------------
// fixup2<STAGE,T>: exact gate for flagged rows from 16 k-partials of type T.
// STAGE 0 (f32 partials): overwrite eidx/s0/c1; re-flag gap<GAPTHR2 rows.
// STAGE 1 (f64 partials): final overwrite.
// ----------------------------------------------------------------------------
template<int STAGE, typename T>
__global__ __launch_bounds__(256)
void fixup2_kernel(const T* __restrict__ zpart, const float* __restrict__ encB,
                   const float* __restrict__ gW, const float* __restrict__ cW,
                   const float* __restrict__ cb, const int* __restrict__ flaglist,
                   const int* __restrict__ nflag, int* __restrict__ eidx,
                   float* __restrict__ s0, float* __restrict__ c1,
                   int* __restrict__ nflag2, int* __restrict__ flaglist2,
                   int fstride, int maxflag)
{
  __shared__ double red[4][10];
  int nf = *nflag; if (nf > maxflag) nf = maxflag;
  const int t = threadIdx.x, lane = t & 63, w = t >> 6;
  for (int f = blockIdx.x; f < nf; f += 128) {
    const int row = flaglist[f];
    double part[10];
#pragma unroll
    for (int i = 0; i < 10; ++i) part[i] = 0.0;
    for (int jj = t; jj < HD; jj += 256) {
      double z = 0.0;
#pragma unroll
      for (int kb = 0; kb < 16; ++kb)
        z += (double)zpart[((size_t)kb * fstride + f) * HD + jj];
      double hj = z + (double)encB[jj];
      hj = hj > 0.0 ? hj : 0.0;
      const float* gr = gW + (size_t)jj * 8;
#pragma unroll
      for (int e2 = 0; e2 < 8; ++e2) part[e2] += hj * (double)gr[e2];
      part[8] += hj * (double)cW[jj * 2];
      part[9] += hj * (double)cW[jj * 2 + 1];
    }
#pragma unroll
    for (int off = 32; off > 0; off >>= 1)
#pragma unroll
      for (int i = 0; i < 10; ++i) part[i] += __shfl_xor(part[i], off);
    if (lane == 0)
#pragma unroll
      for (int i = 0; i < 10; ++i) red[w][i] = part[i];
    __syncthreads();
    if (t == 0) {
      double a[10];
#pragma unroll
      for (int i = 0; i < 10; ++i)
        a[i] = red[0][i] + red[1][i] + red[2][i] + red[3][i];
      int best = 0; double bm = a[0];
#pragma unroll
      for (int e2 = 1; e2 < 8; ++e2) if (a[e2] > bm) { bm = a[e2]; best = e2; }
      double sec = -1.0e300;
#pragma unroll
      for (int e2 = 0; e2 < 8; ++e2) if (e2 != best && a[e2] > sec) sec = a[e2];
      double s = 0.0;
#pragma unroll
      for (int e2 = 0; e2 < 8; ++e2) s += exp(a[e2] - bm);
      const double p  = 1.0 / s;
      const double l0 = a[8] + (double)cb[0], l1 = a[9] + (double)cb[1];
      const double mx = l0 > l1 ? l0 : l1;
      const double e0 = exp(l0 - mx), e1 = exp(l1 - mx);
      const double inv = 1.0 / (e0 + e1);
      eidx[row] = best;
      s0[row]   = (float)(p * e0 * inv);
      c1[row]   = (float)(e1 * inv);
      if constexpr (STAGE == 0) {
        if (bm - sec < GAPTHR2) {
          int fi = atomicAdd(nflag2, 1);
          if (fi < MAXFLAG2) flaglist2[fi] = row;
        }
      }
    }
    __syncthreads();
  }
}

__global__ __launch_bounds__(256)
void count_kernel(const int* __restrict__ eidx, unsigned* __restrict__ cnt) {
  const int n = blockIdx.x * 256 + threadIdx.x;
  atomicAdd(&cnt[eidx[n]], 1u);
}

__global__ void scan_kernel(const unsigned* __restrict__ cnt,
                            int* __restrict__ tinfo, int* __restrict__ offs,
                            int* __restrict__ cursor) {
  if (threadIdx.x == 0 && blockIdx.x == 0) {
    int off = 0, nt = 0;
    for (int e = 0; e < NEXP; ++e) {
      offs[e] = off; cursor[e] = 0;
      const int c = (int)cnt[e];
      const int end = off + c;
      for (int r = 0; r < c; r += 128) {
        tinfo[1 + nt * 3 + 0] = e;
        tinfo[1 + nt * 3 + 1] = off + r;
        tinfo[1 + nt * 3 + 2] = end;
        ++nt;
      }
      off = end;
    }
    tinfo[0] = nt;
  }
}

__global__ __launch_bounds__(256)
void scatter_kernel(const int* __restrict__ eidx, const int* __restrict__ offs,
                    int* __restrict__ cursor, int* __restrict__ rowperm) {
  const int n = blockIdx.x * 256 + threadIdx.x;
  const int e = eidx[n];
  rowperm[offs[e] + atomicAdd(&cursor[e], 1)] = n;
}

// ----------------------------------------------------------------------------
extern "C" void kernel_launch(void* const* d_in, const int* in_sizes, int n_in,
                              void* d_out, int out_size, void* d_ws, size_t ws_size,
                              hipStream_t stream) {
  (void)in_sizes; (void)n_in; (void)out_size;
  const float* x      = (const float*)d_in[0];
  const float* enc_W  = (const float*)d_in[1];
  const float* enc_b  = (const float*)d_in[2];
  const float* gate_W = (const float*)d_in[3];
  const float* exp_W  = (const float*)d_in[4];
  const float* exp_b  = (const float*)d_in[5];
  const float* mlp_W  = (const float*)d_in[6];
  const float* mlp_b  = (const float*)d_in[7];
  const float* coef_W = (const float*)d_in[8];
  const float* coef_b = (const float*)d_in[9];
  const float* dec_W  = (const float*)d_in[10];
  const float* dec_b  = (const float*)d_in[11];

  char* ws = (char*)d_ws;
  size_t off = 0;
  auto alloc = [&](size_t bytes) {
    char* p = ws + off;
    off += (bytes + 255) & ~(size_t)255;
    return p;
  };
  uint16_t* encWT  = (uint16_t*)alloc((size_t)DIN * HD * 2);          //  4 MiB
  uint16_t* mlpWT  = (uint16_t*)alloc((size_t)HD * HD * 2);           //  2 MiB
  uint16_t* decWT  = (uint16_t*)alloc((size_t)HD * DIN * 2);          //  4 MiB
  uint16_t* expWT  = (uint16_t*)alloc((size_t)NEXP * HD * HD * 2);    // 16 MiB
  uint16_t* h_bf   = (uint16_t*)alloc((size_t)NROWS * HD * 2);        // 16 MiB
  float*    zpart  = (float*)   alloc((size_t)16 * MAXFLAG * HD * 4); // 32 MiB
  int*      eidx   = (int*)     alloc(NROWS * 4);
  float*    s0     = (float*)   alloc(NROWS * 4);
  float*    c1     = (float*)   alloc(NROWS * 4);
  int*      rowperm= (int*)     alloc(NROWS * 4);
  int*      flags  = (int*)     alloc(MAXFLAG * 4);
  int*      flags2 = (int*)     alloc(MAXFLAG2 * 4);
  char*     ctrs   = (char*)    alloc(256);
  int*      offs   = (int*)     alloc(64);
  int*      cursor = (int*)     alloc(64);
  int*      tinfo  = (int*)     alloc((1 + MAX_TILES * 3) * 4 + 64);
  // Lifetime-disjoint aliases of the 32 MiB zpart region:
  //   x_bf   [cast, enc GEMM)         33.55 MB... (16.78 MB actual: NROWS*DIN*2 = 33.6MB)
  //   zpart  [fixup1a, fixup2a)       16*512*1024*4  = 33.6 MB
  //   zpartB [fixup1b, fixup2b)       16*128*1024*8  = 16.8 MB
  //   accout [exp GEMM, dec GEMM)     NROWS*HD*2     = 16.8 MB
  uint16_t* x_bf   = (uint16_t*)zpart;
  double*   zpartB = (double*)zpart;
  uint16_t* accout = (uint16_t*)zpart;
  unsigned* cnt    = (unsigned*)ctrs;
  int*      nflag  = (int*)(ctrs + 32);
  int*      nflag2 = (int*)(ctrs + 64);
  if (off > ws_size) return;

  hipMemsetAsync(ctrs, 0, 256, stream);

  const dim3 blk(256);
  cast_k<<<dim3(1024), blk, 0, stream>>>(x, x_bf, NROWS * DIN / 8);
  tcast_k<<<dim3(HD / 64, DIN / 64, 1),    blk, 0, stream>>>(enc_W, encWT, DIN, HD);
  tcast_k<<<dim3(HD / 64, HD / 64, 1),     blk, 0, stream>>>(mlp_W, mlpWT, HD, HD);
  tcast_k<<<dim3(DIN / 64, HD / 64, 1),    blk, 0, stream>>>(dec_W, decWT, HD, DIN);
  tcast_k<<<dim3(HD / 64, HD / 64, NEXP),  blk, 0, stream>>>(exp_W, expWT, HD, HD);

  gemm_kernel<0><<<dim3(NROWS / 128, HD / 128), blk, 0, stream>>>(
      x_bf, encWT, h_bf, nullptr, enc_b, nullptr, nullptr, nullptr,
      NROWS, HD, DIN);

  gate_kernel<<<dim3(NROWS / 4), blk, 0, stream>>>(
      h_bf, gate_W, coef_W, coef_b, eidx, s0, c1, nflag, flags);

  // stage a: f32 screen over ~345 rows
  fixup1_kernel<float><<<dim3(16, 16, F1Z), blk, 0, stream>>>(
      x, enc_W, flags, nflag, zpart, MAXFLAG, MAXFLAG);
  fixup2_kernel<0, float><<<dim3(128), blk, 0, stream>>>(
      zpart, enc_b, gate_W, coef_W, coef_b, flags, nflag, eidx, s0, c1,
      nflag2, flags2, MAXFLAG, MAXFLAG);
  // stage b: f64 arbiter over the ~20 survivors
  fixup1_kernel<double><<<dim3(16, 16, F1Z), blk, 0, stream>>>(
      x, enc_W, flags2, nflag2, zpartB, MAXFLAG2, MAXFLAG2);
  fixup2_kernel<1, double><<<dim3(128), blk, 0, stream>>>(
      zpartB, enc_b, gate_W, coef_W, coef_b, flags2, nflag2, eidx, s0, c1,
      nullptr, nullptr, MAXFLAG2, MAXFLAG2);

  count_kernel<<<dim3(NROWS / 256), blk, 0, stream>>>(eidx, cnt);
  scan_kernel<<<1, 64, 0, stream>>>(cnt, tinfo, offs, cursor);
  scatter_kernel<<<dim3(NROWS / 256), blk, 0, stream>>>(eidx, offs, cursor, rowperm);

  gemm_kernel<1><<<dim3(MAX_TILES, HD / 128), blk, 0, stream>>>(
      h_bf, expWT, accout, nullptr, exp_b, rowperm, tinfo, s0,
      NROWS, HD, HD);
  gemm_kernel<2><<<dim3(NROWS / 128, HD / 128), blk, 0, stream>>>(
      h_bf, mlpWT, accout, nullptr, mlp_b, nullptr, nullptr, c1,
      NROWS, HD, HD);
  gemm_kernel<3><<<dim3(NROWS / 128, DIN / 128), blk, 0, stream>>>(
      accout, decWT, nullptr, (float*)d_out, dec_b, nullptr, nullptr, nullptr,
      NROWS, DIN, HD);
}